// Round 1
// baseline (1321.915 us; speedup 1.0000x reference)
//
#include <hip/hip_runtime.h>
#include <cstdint>
#include <cstddef>

#define BB 32
#define GG 50
#define CC 80
#define AA 8400
#define PCH (5 + CC)   // pred_output channels = 85

__device__ __forceinline__ float logsigf(float x) {
    // log_sigmoid(x) = min(x,0) - log1p(exp(-|x|))
    return fminf(x, 0.f) - log1pf(expf(-fabsf(x)));
}
__device__ __forceinline__ float softplusf(float x) {
    return fmaxf(x, 0.f) + log1pf(expf(-fabsf(x)));
}

// ---------------- K1: per-anchor class-sum precompute ----------------
__global__ void k_precompute(const float* __restrict__ obj, const float* __restrict__ cls,
                             float* __restrict__ s_neg, float* __restrict__ sps) {
    int i = blockIdx.x * blockDim.x + threadIdx.x;  // b*AA + a
    if (i >= BB * AA) return;
    float o = obj[i];
    float lo = logsigf(o);
    const float* c = cls + (size_t)i * CC;
    float sn = 0.f, sp = 0.f;
    for (int j = 0; j < CC; j++) {
        float x = c[j];
        sp += softplusf(x);
        float lq = 0.5f * (logsigf(x) + lo);
        float q = expf(lq);
        q = fminf(fmaxf(q, 1e-7f), 1.f - 1e-7f);
        sn += log1pf(-q);
    }
    s_neg[i] = sn;
    sps[i] = sp;
}

// ---------------- K2: geometry (fg0 + and_ctr bitmask) ----------------
__global__ void k_geom(const float* __restrict__ labels, const float* __restrict__ xs,
                       const float* __restrict__ ys, const float* __restrict__ ss,
                       int* __restrict__ fg0, unsigned long long* __restrict__ amask) {
    int b = blockIdx.y;
    int a = blockIdx.x * blockDim.x + threadIdx.x;
    __shared__ float lab[GG * 5];
    __shared__ int lv[GG];
    for (int t = threadIdx.x; t < GG * 5; t += blockDim.x) lab[t] = labels[b * GG * 5 + t];
    __syncthreads();
    if (threadIdx.x < GG) {
        const float* r = lab + threadIdx.x * 5;
        lv[threadIdx.x] = ((r[0] + r[1] + r[2] + r[3] + r[4]) > 0.f) ? 1 : 0;
    }
    __syncthreads();
    if (a >= AA) return;
    float s = ss[a];
    float xc = (xs[a] + 0.5f) * s;
    float yc = (ys[a] + 0.5f) * s;
    unsigned long long m = 0;
    int any = 0;
    for (int g = 0; g < GG; g++) {
        if (!lv[g]) continue;
        const float* r = lab + g * 5;
        float gx = r[1], gy = r[2], gw = r[3], gh = r[4];
        float d1 = xc - (gx - gw * 0.5f);
        float d2 = (gx + gw * 0.5f) - xc;
        float d3 = yc - (gy - gh * 0.5f);
        float d4 = (gy + gh * 0.5f) - yc;
        bool ib = fminf(fminf(d1, d2), fminf(d3, d4)) > 0.f;
        float cr = 2.5f * s;
        float e1 = xc - (gx - cr);
        float e2 = (gx + cr) - xc;
        float e3 = yc - (gy - cr);
        float e4 = (gy + cr) - yc;
        bool ic = fminf(fminf(e1, e2), fminf(e3, e4)) > 0.f;
        if (ib || ic) any = 1;
        if (ib && ic) m |= 1ull << g;
    }
    fg0[b * AA + a] = any;
    amask[b * AA + a] = m;
}

// ---------------- K3: cost + masked iou matrices ----------------
__global__ void k_cost(const float* __restrict__ pred, const float* __restrict__ obj,
                       const float* __restrict__ cls, const float* __restrict__ labels,
                       const float* __restrict__ s_neg, const int* __restrict__ fg0,
                       const unsigned long long* __restrict__ amask,
                       float* __restrict__ cost, float* __restrict__ iou) {
    int b = blockIdx.z, g = blockIdx.y;
    int a = blockIdx.x * blockDim.x + threadIdx.x;
    if (a >= AA) return;
    const float* r = labels + (size_t)(b * GG + g) * 5;
    float gcls = r[0], gx = r[1], gy = r[2], gw = r[3], gh = r[4];
    bool valid = (gcls + gx + gy + gw + gh) > 0.f;
    int gtc = (int)gcls;
    int ia = b * AA + a;
    const float* p = pred + (size_t)ia * PCH;
    float px = p[0], py = p[1], pw = p[2], ph = p[3];
    // pairwise IoU (cxcywh)
    float tlx = fmaxf(gx - gw * 0.5f, px - pw * 0.5f);
    float tly = fmaxf(gy - gh * 0.5f, py - ph * 0.5f);
    float brx = fminf(gx + gw * 0.5f, px + pw * 0.5f);
    float bry = fminf(gy + gh * 0.5f, py + ph * 0.5f);
    float en = (tlx < brx && tly < bry) ? 1.f : 0.f;
    float ai = (brx - tlx) * (bry - tly) * en;
    float v = ai / (gw * gh + pw * ph - ai + 1e-16f);
    int f0 = fg0[ia];
    v = v * (f0 ? 1.f : 0.f) * (valid ? 1.f : 0.f);
    // cls cost
    float o = obj[ia];
    float x = cls[(size_t)ia * CC + gtc];
    float lq = 0.5f * (logsigf(x) + logsigf(o));
    float q = fminf(fmaxf(expf(lq), 1e-7f), 1.f - 1e-7f);
    float cc = -logf(q) + log1pf(-q) - s_neg[ia];
    bool ac = (amask[ia] >> g) & 1ull;
    float cst = cc - 3.0f * logf(v + 1e-8f);
    cst += 100000.0f * (ac ? 0.f : 1.f);
    cst += 1000000000.0f * ((!f0 || !valid) ? 1.f : 0.f);
    size_t idx = (size_t)(b * GG + g) * AA + a;
    cost[idx] = cst;
    iou[idx] = v;
}

// ---------------- K4: dyn_k = max(int(sum top-10 iou), 1) per (b,g) ----------------
__global__ void k_dynk(const float* __restrict__ iou, int* __restrict__ dynk) {
    int w = (blockIdx.x * blockDim.x + threadIdx.x) / 64;
    int lane = threadIdx.x & 63;
    if (w >= BB * GG) return;
    const float* row = iou + (size_t)w * AA;
    int chosen[10];
    float sum = 0.f;
    for (int p = 0; p < 10; p++) {
        float bv = -1.f;
        int bi = AA;
        for (int a = lane; a < AA; a += 64) {
            float v = row[a];
            bool skip = false;
            for (int t = 0; t < p; t++)
                if (chosen[t] == a) skip = true;
            if (!skip && (v > bv || (v == bv && a < bi))) { bv = v; bi = a; }
        }
        for (int off = 32; off; off >>= 1) {
            float ov = __shfl_xor(bv, off);
            int oi = __shfl_xor(bi, off);
            if (ov > bv || (ov == bv && oi < bi)) { bv = ov; bi = oi; }
        }
        chosen[p] = bi;
        sum += bv;
    }
    if (lane == 0) {
        int k = (int)sum;
        if (k < 1) k = 1;
        dynk[w] = k;
    }
}

// ---------------- K5: top-k (smallest cost) selection per (b,g) ----------------
__global__ void k_select(const float* __restrict__ cost, const float* __restrict__ labels,
                         const int* __restrict__ dynk, unsigned long long* __restrict__ mmask) {
    int w = (blockIdx.x * blockDim.x + threadIdx.x) / 64;
    int lane = threadIdx.x & 63;
    if (w >= BB * GG) return;
    int b = w / GG, g = w % GG;
    const float* r = labels + (size_t)w * 5;
    if (!((r[0] + r[1] + r[2] + r[3] + r[4]) > 0.f)) return;  // invalid gt: no matches
    const float* row = cost + (size_t)w * AA;
    int k = dynk[w];
    int chosen[10];
    for (int p = 0; p < k; p++) {
        float bv = 3.4e38f;
        int bi = AA;
        for (int a = lane; a < AA; a += 64) {
            float v = row[a];
            bool skip = false;
            for (int t = 0; t < p; t++)
                if (chosen[t] == a) skip = true;
            if (!skip && (v < bv || (v == bv && a < bi))) { bv = v; bi = a; }
        }
        for (int off = 32; off; off >>= 1) {
            float ov = __shfl_xor(bv, off);
            int oi = __shfl_xor(bi, off);
            if (ov < bv || (ov == bv && oi < bi)) { bv = ov; bi = oi; }
        }
        chosen[p] = bi;
        if (lane == 0) atomicOr(&mmask[(size_t)b * AA + bi], 1ull << g);
    }
}

// ---------------- K6: resolve multi-match + loss partials ----------------
__global__ void k_loss(const float* __restrict__ pred, const float* __restrict__ obj,
                       const float* __restrict__ cls, const float* __restrict__ labels,
                       const float* __restrict__ cost, const float* __restrict__ iou,
                       const unsigned long long* __restrict__ mmask,
                       const float* __restrict__ sps, float* __restrict__ accum) {
    int i = blockIdx.x * blockDim.x + threadIdx.x;
    float li = 0.f, lo = 0.f, lc = 0.f, nf = 0.f;
    if (i < BB * AA) {
        int b = i / AA, a = i % AA;
        unsigned long long m = mmask[i];
        int cnt = __popcll(m);
        bool fg = (m != 0);
        int mg = 0;
        if (cnt > 1) {
            float bv = 3.4e38f;
            for (int g = 0; g < GG; g++) {
                float v = cost[(size_t)(b * GG + g) * AA + a];
                if (v < bv) { bv = v; mg = g; }
            }
        } else if (cnt == 1) {
            mg = __ffsll((unsigned long long)m) - 1;
        }
        float o = obj[i];
        lo = softplusf(o) - (fg ? o : 0.f);
        if (fg) {
            float piou = iou[(size_t)(b * GG + mg) * AA + a];
            const float* r = labels + (size_t)(b * GG + mg) * 5;
            int gtc = (int)r[0];
            float gx = r[1], gy = r[2], gw = r[3], gh = r[4];
            const float* p = pred + (size_t)i * PCH;
            float px = p[0], py = p[1], pw = p[2], ph = p[3];
            float tlx = fmaxf(px - pw * 0.5f, gx - gw * 0.5f);
            float tly = fmaxf(py - ph * 0.5f, gy - gh * 0.5f);
            float brx = fminf(px + pw * 0.5f, gx + gw * 0.5f);
            float bry = fminf(py + ph * 0.5f, gy + gh * 0.5f);
            float en = (tlx < brx && tly < bry) ? 1.f : 0.f;
            float ai = (brx - tlx) * (bry - tly) * en;
            float u = pw * ph + gw * gh - ai;
            float v2 = ai / (u + 1e-16f);
            li = 1.f - v2 * v2;
            lc = sps[i] - cls[(size_t)i * CC + gtc] * piou;
            nf = 1.f;
        }
    }
    // wave reduction, one atomic set per wave
    for (int off = 32; off; off >>= 1) {
        li += __shfl_down(li, off);
        lo += __shfl_down(lo, off);
        lc += __shfl_down(lc, off);
        nf += __shfl_down(nf, off);
    }
    if ((threadIdx.x & 63) == 0) {
        atomicAdd(&accum[0], li);
        atomicAdd(&accum[1], lo);
        atomicAdd(&accum[2], lc);
        atomicAdd(&accum[3], nf);
    }
}

// ---------------- K7: finalize ----------------
__global__ void k_final(const float* __restrict__ accum, float* __restrict__ out) {
    float nf = fmaxf(accum[3], 1.f);
    out[0] = (5.f * accum[0] + accum[1] + accum[2]) / nf;
}

extern "C" void kernel_launch(void* const* d_in, const int* in_sizes, int n_in,
                              void* d_out, int out_size, void* d_ws, size_t ws_size,
                              hipStream_t stream) {
    const float* pred = (const float*)d_in[0];   // (B,A,85)
    const float* obj  = (const float*)d_in[1];   // (B,A,1)
    const float* cls  = (const float*)d_in[2];   // (B,A,80)
    const float* lab  = (const float*)d_in[3];   // (B,G,5)
    const float* xs   = (const float*)d_in[4];   // (A,)
    const float* ys   = (const float*)d_in[5];   // (A,)
    const float* ss   = (const float*)d_in[6];   // (A,)
    float* out = (float*)d_out;

    const size_t BA = (size_t)BB * AA;
    const size_t BGA = (size_t)BB * GG * AA;

    float* cost = (float*)d_ws;                    // BGA f32
    float* iou  = cost + BGA;                      // BGA f32
    float* sneg = iou + BGA;                       // BA f32
    float* sps  = sneg + BA;                       // BA f32
    int*   fg0  = (int*)(sps + BA);                // BA i32
    unsigned long long* amask = (unsigned long long*)(fg0 + BA);  // BA u64
    unsigned long long* mmask = amask + BA;        // BA u64
    int* dynk = (int*)(mmask + BA);                // B*G i32
    float* accum = (float*)(dynk + BB * GG);       // 4 f32

    // zero the accumulation targets (atomicOr / atomicAdd destinations)
    hipMemsetAsync(mmask, 0, BA * sizeof(unsigned long long), stream);
    hipMemsetAsync(accum, 0, 4 * sizeof(float), stream);

    dim3 blk(256);
    // K1
    k_precompute<<<dim3((BB * AA + 255) / 256), blk, 0, stream>>>(obj, cls, sneg, sps);
    // K2
    k_geom<<<dim3((AA + 255) / 256, BB), blk, 0, stream>>>(lab, xs, ys, ss, fg0, amask);
    // K3
    k_cost<<<dim3((AA + 255) / 256, GG, BB), blk, 0, stream>>>(pred, obj, cls, lab, sneg,
                                                               fg0, amask, cost, iou);
    // K4: one wave per (b,g) -> 1600 waves, 4 waves/block
    k_dynk<<<dim3((BB * GG + 3) / 4), blk, 0, stream>>>(iou, dynk);
    // K5
    k_select<<<dim3((BB * GG + 3) / 4), blk, 0, stream>>>(cost, lab, dynk, mmask);
    // K6
    k_loss<<<dim3((BB * AA + 255) / 256), blk, 0, stream>>>(pred, obj, cls, lab, cost, iou,
                                                            mmask, sps, accum);
    // K7
    k_final<<<1, 1, 0, stream>>>(accum, out);
}

// Round 2
// 676.243 us; speedup vs baseline: 1.9548x; 1.9548x over previous
//
#include <hip/hip_runtime.h>
#include <cstdint>
#include <cstddef>

#define BB 32
#define GG 50
#define CC 80
#define AA 8400
#define PCH (5 + CC)   // pred_output channels = 85
#define LP 11          // LDS list stride (pad 10 -> 11: conflict-free)

__device__ __forceinline__ float logsigf(float x) {
    // log_sigmoid(x) = min(x,0) - log1p(exp(-|x|))
    return fminf(x, 0.f) - log1pf(expf(-fabsf(x)));
}
__device__ __forceinline__ float softplusf(float x) {
    return fmaxf(x, 0.f) + log1pf(expf(-fabsf(x)));
}

// ---------------- K1: per-anchor class-sum precompute ----------------
__global__ void k_precompute(const float* __restrict__ obj, const float* __restrict__ cls,
                             float* __restrict__ s_neg, float* __restrict__ sps) {
    int i = blockIdx.x * blockDim.x + threadIdx.x;  // b*AA + a
    if (i >= BB * AA) return;
    float o = obj[i];
    float lo = logsigf(o);
    const float* c = cls + (size_t)i * CC;
    float sn = 0.f, sp = 0.f;
    for (int j = 0; j < CC; j++) {
        float x = c[j];
        sp += softplusf(x);
        float lq = 0.5f * (logsigf(x) + lo);
        float q = expf(lq);
        q = fminf(fmaxf(q, 1e-7f), 1.f - 1e-7f);
        sn += log1pf(-q);
    }
    s_neg[i] = sn;
    sps[i] = sp;
}

// ---------------- K2: geometry (fg0 + and_ctr bitmask) ----------------
__global__ void k_geom(const float* __restrict__ labels, const float* __restrict__ xs,
                       const float* __restrict__ ys, const float* __restrict__ ss,
                       int* __restrict__ fg0, unsigned long long* __restrict__ amask) {
    int b = blockIdx.y;
    int a = blockIdx.x * blockDim.x + threadIdx.x;
    __shared__ float lab[GG * 5];
    __shared__ int lv[GG];
    for (int t = threadIdx.x; t < GG * 5; t += blockDim.x) lab[t] = labels[b * GG * 5 + t];
    __syncthreads();
    if (threadIdx.x < GG) {
        const float* r = lab + threadIdx.x * 5;
        lv[threadIdx.x] = ((r[0] + r[1] + r[2] + r[3] + r[4]) > 0.f) ? 1 : 0;
    }
    __syncthreads();
    if (a >= AA) return;
    float s = ss[a];
    float xc = (xs[a] + 0.5f) * s;
    float yc = (ys[a] + 0.5f) * s;
    unsigned long long m = 0;
    int any = 0;
    for (int g = 0; g < GG; g++) {
        if (!lv[g]) continue;
        const float* r = lab + g * 5;
        float gx = r[1], gy = r[2], gw = r[3], gh = r[4];
        float d1 = xc - (gx - gw * 0.5f);
        float d2 = (gx + gw * 0.5f) - xc;
        float d3 = yc - (gy - gh * 0.5f);
        float d4 = (gy + gh * 0.5f) - yc;
        bool ib = fminf(fminf(d1, d2), fminf(d3, d4)) > 0.f;
        float cr = 2.5f * s;
        float e1 = xc - (gx - cr);
        float e2 = (gx + cr) - xc;
        float e3 = yc - (gy - cr);
        float e4 = (gy + cr) - yc;
        bool ic = fminf(fminf(e1, e2), fminf(e3, e4)) > 0.f;
        if (ib || ic) any = 1;
        if (ib && ic) m |= 1ull << g;
    }
    fg0[b * AA + a] = any;
    amask[b * AA + a] = m;
}

// ---------------- K3: cost + masked iou matrices ----------------
__global__ void k_cost(const float* __restrict__ pred, const float* __restrict__ obj,
                       const float* __restrict__ cls, const float* __restrict__ labels,
                       const float* __restrict__ s_neg, const int* __restrict__ fg0,
                       const unsigned long long* __restrict__ amask,
                       float* __restrict__ cost, float* __restrict__ iou) {
    int b = blockIdx.z, g = blockIdx.y;
    int a = blockIdx.x * blockDim.x + threadIdx.x;
    if (a >= AA) return;
    const float* r = labels + (size_t)(b * GG + g) * 5;
    float gcls = r[0], gx = r[1], gy = r[2], gw = r[3], gh = r[4];
    bool valid = (gcls + gx + gy + gw + gh) > 0.f;
    int gtc = (int)gcls;
    int ia = b * AA + a;
    const float* p = pred + (size_t)ia * PCH;
    float px = p[0], py = p[1], pw = p[2], ph = p[3];
    // pairwise IoU (cxcywh)
    float tlx = fmaxf(gx - gw * 0.5f, px - pw * 0.5f);
    float tly = fmaxf(gy - gh * 0.5f, py - ph * 0.5f);
    float brx = fminf(gx + gw * 0.5f, px + pw * 0.5f);
    float bry = fminf(gy + gh * 0.5f, py + ph * 0.5f);
    float en = (tlx < brx && tly < bry) ? 1.f : 0.f;
    float ai = (brx - tlx) * (bry - tly) * en;
    float v = ai / (gw * gh + pw * ph - ai + 1e-16f);
    int f0 = fg0[ia];
    v = v * (f0 ? 1.f : 0.f) * (valid ? 1.f : 0.f);
    // cls cost
    float o = obj[ia];
    float x = cls[(size_t)ia * CC + gtc];
    float lq = 0.5f * (logsigf(x) + logsigf(o));
    float q = fminf(fmaxf(expf(lq), 1e-7f), 1.f - 1e-7f);
    float cc = -logf(q) + log1pf(-q) - s_neg[ia];
    bool ac = (amask[ia] >> g) & 1ull;
    float cst = cc - 3.0f * logf(v + 1e-8f);
    cst += 100000.0f * (ac ? 0.f : 1.f);
    cst += 1000000000.0f * ((!f0 || !valid) ? 1.f : 0.f);
    size_t idx = (size_t)(b * GG + g) * AA + a;
    cost[idx] = cst;
    iou[idx] = v;
}

// ---------------- K4+K5 fused: single-pass dyn_k + top-k selection per (b,g) ----
// One 256-thread block per (b,g). Each thread keeps:
//   iv[10]  : its 10 largest ious (descending)
//   cv/ci[10]: its 10 smallest (cost, idx) pairs (ascending, tie -> lower idx)
// then an LDS tree-merge (256 sorted lists -> 1) gives the exact global top-10s.
__global__ void k_assign(const float* __restrict__ cost, const float* __restrict__ iou,
                         const float* __restrict__ labels,
                         unsigned long long* __restrict__ mmask) {
    int w = blockIdx.x;          // b*GG + g
    int b = w / GG, g = w % GG;
    const float* r = labels + (size_t)w * 5;
    if (!((r[0] + r[1] + r[2] + r[3] + r[4]) > 0.f)) return;  // invalid gt (uniform)
    int tid = threadIdx.x;
    const float* crow = cost + (size_t)w * AA;
    const float* irow = iou + (size_t)w * AA;

    float iv[10];
    float cv[10];
    int ci[10];
#pragma unroll
    for (int t = 0; t < 10; t++) { iv[t] = 0.f; cv[t] = 3.4e38f; ci[t] = AA; }

    for (int a = tid; a < AA; a += 256) {
        float u = irow[a];
        if (u > iv[9]) {
#pragma unroll
            for (int t = 0; t < 10; t++)
                if (u > iv[t]) { float tmp = iv[t]; iv[t] = u; u = tmp; }
        }
        float v = crow[a];
        int idx = a;
        if (v < cv[9] || (v == cv[9] && idx < ci[9])) {
#pragma unroll
            for (int t = 0; t < 10; t++) {
                bool sw = (v < cv[t]) || (v == cv[t] && idx < ci[t]);
                if (sw) {
                    float tf = cv[t]; cv[t] = v; v = tf;
                    int ti = ci[t]; ci[t] = idx; idx = ti;
                }
            }
        }
    }

    __shared__ float Lv[256 * LP];
    __shared__ int Li[256 * LP];
    __shared__ int s_k;

    // ---- Phase A: merge iou lists (descending), compute dyn_k ----
#pragma unroll
    for (int t = 0; t < 10; t++) Lv[tid * LP + t] = iv[t];
    __syncthreads();
    for (int n = 256; n > 1; n >>= 1) {
        float out[10];
        int half = n >> 1;
        if (tid < half) {
            int ia = (2 * tid) * LP, ib = (2 * tid + 1) * LP;
#pragma unroll
            for (int j = 0; j < 10; j++) {
                float av = Lv[ia], bv = Lv[ib];
                if (av >= bv) { out[j] = av; ia++; }
                else          { out[j] = bv; ib++; }
            }
        }
        __syncthreads();
        if (tid < half) {
#pragma unroll
            for (int j = 0; j < 10; j++) Lv[tid * LP + j] = out[j];
        }
        __syncthreads();
    }
    if (tid == 0) {
        float s = 0.f;
#pragma unroll
        for (int j = 0; j < 10; j++) s += Lv[j];
        int k = (int)s;
        if (k < 1) k = 1;
        s_k = k;
    }
    __syncthreads();

    // ---- Phase B: merge (cost, idx) lists (ascending, tie by lower idx) ----
#pragma unroll
    for (int t = 0; t < 10; t++) { Lv[tid * LP + t] = cv[t]; Li[tid * LP + t] = ci[t]; }
    __syncthreads();
    for (int n = 256; n > 1; n >>= 1) {
        float ov[10];
        int oi[10];
        int half = n >> 1;
        if (tid < half) {
            int ia = (2 * tid) * LP, ib = (2 * tid + 1) * LP;
#pragma unroll
            for (int j = 0; j < 10; j++) {
                float av = Lv[ia], bv = Lv[ib];
                int ax = Li[ia], bx = Li[ib];
                bool ta = (av < bv) || (av == bv && ax < bx);
                if (ta) { ov[j] = av; oi[j] = ax; ia++; }
                else    { ov[j] = bv; oi[j] = bx; ib++; }
            }
        }
        __syncthreads();
        if (tid < half) {
#pragma unroll
            for (int j = 0; j < 10; j++) { Lv[tid * LP + j] = ov[j]; Li[tid * LP + j] = oi[j]; }
        }
        __syncthreads();
    }

    if (tid < s_k) {
        atomicOr(&mmask[(size_t)b * AA + Li[tid]], 1ull << g);
    }
}

// ---------------- K6: resolve multi-match + loss partials ----------------
__global__ void k_loss(const float* __restrict__ pred, const float* __restrict__ obj,
                       const float* __restrict__ cls, const float* __restrict__ labels,
                       const float* __restrict__ cost, const float* __restrict__ iou,
                       const unsigned long long* __restrict__ mmask,
                       const float* __restrict__ sps, float* __restrict__ accum) {
    int i = blockIdx.x * blockDim.x + threadIdx.x;
    float li = 0.f, lo = 0.f, lc = 0.f, nf = 0.f;
    if (i < BB * AA) {
        int b = i / AA, a = i % AA;
        unsigned long long m = mmask[i];
        int cnt = __popcll(m);
        bool fg = (m != 0);
        int mg = 0;
        if (cnt > 1) {
            float bv = 3.4e38f;
            for (int g = 0; g < GG; g++) {
                float v = cost[(size_t)(b * GG + g) * AA + a];
                if (v < bv) { bv = v; mg = g; }
            }
        } else if (cnt == 1) {
            mg = __ffsll((unsigned long long)m) - 1;
        }
        float o = obj[i];
        lo = softplusf(o) - (fg ? o : 0.f);
        if (fg) {
            float piou = iou[(size_t)(b * GG + mg) * AA + a];
            const float* r = labels + (size_t)(b * GG + mg) * 5;
            int gtc = (int)r[0];
            float gx = r[1], gy = r[2], gw = r[3], gh = r[4];
            const float* p = pred + (size_t)i * PCH;
            float px = p[0], py = p[1], pw = p[2], ph = p[3];
            float tlx = fmaxf(px - pw * 0.5f, gx - gw * 0.5f);
            float tly = fmaxf(py - ph * 0.5f, gy - gh * 0.5f);
            float brx = fminf(px + pw * 0.5f, gx + gw * 0.5f);
            float bry = fminf(py + ph * 0.5f, gy + gh * 0.5f);
            float en = (tlx < brx && tly < bry) ? 1.f : 0.f;
            float ai = (brx - tlx) * (bry - tly) * en;
            float u = pw * ph + gw * gh - ai;
            float v2 = ai / (u + 1e-16f);
            li = 1.f - v2 * v2;
            lc = sps[i] - cls[(size_t)i * CC + gtc] * piou;
            nf = 1.f;
        }
    }
    // wave reduction, one atomic set per wave
    for (int off = 32; off; off >>= 1) {
        li += __shfl_down(li, off);
        lo += __shfl_down(lo, off);
        lc += __shfl_down(lc, off);
        nf += __shfl_down(nf, off);
    }
    if ((threadIdx.x & 63) == 0) {
        atomicAdd(&accum[0], li);
        atomicAdd(&accum[1], lo);
        atomicAdd(&accum[2], lc);
        atomicAdd(&accum[3], nf);
    }
}

// ---------------- K7: finalize ----------------
__global__ void k_final(const float* __restrict__ accum, float* __restrict__ out) {
    float nf = fmaxf(accum[3], 1.f);
    out[0] = (5.f * accum[0] + accum[1] + accum[2]) / nf;
}

extern "C" void kernel_launch(void* const* d_in, const int* in_sizes, int n_in,
                              void* d_out, int out_size, void* d_ws, size_t ws_size,
                              hipStream_t stream) {
    const float* pred = (const float*)d_in[0];   // (B,A,85)
    const float* obj  = (const float*)d_in[1];   // (B,A,1)
    const float* cls  = (const float*)d_in[2];   // (B,A,80)
    const float* lab  = (const float*)d_in[3];   // (B,G,5)
    const float* xs   = (const float*)d_in[4];   // (A,)
    const float* ys   = (const float*)d_in[5];   // (A,)
    const float* ss   = (const float*)d_in[6];   // (A,)
    float* out = (float*)d_out;

    const size_t BA = (size_t)BB * AA;
    const size_t BGA = (size_t)BB * GG * AA;

    float* cost = (float*)d_ws;                    // BGA f32
    float* iou  = cost + BGA;                      // BGA f32
    float* sneg = iou + BGA;                       // BA f32
    float* sps  = sneg + BA;                       // BA f32
    int*   fg0  = (int*)(sps + BA);                // BA i32
    unsigned long long* amask = (unsigned long long*)(fg0 + BA);  // BA u64
    unsigned long long* mmask = amask + BA;        // BA u64
    float* accum = (float*)(mmask + BA);           // 4 f32

    // zero the accumulation targets (atomicOr / atomicAdd destinations)
    hipMemsetAsync(mmask, 0, BA * sizeof(unsigned long long), stream);
    hipMemsetAsync(accum, 0, 4 * sizeof(float), stream);

    dim3 blk(256);
    // K1
    k_precompute<<<dim3((BB * AA + 255) / 256), blk, 0, stream>>>(obj, cls, sneg, sps);
    // K2
    k_geom<<<dim3((AA + 255) / 256, BB), blk, 0, stream>>>(lab, xs, ys, ss, fg0, amask);
    // K3
    k_cost<<<dim3((AA + 255) / 256, GG, BB), blk, 0, stream>>>(pred, obj, cls, lab, sneg,
                                                               fg0, amask, cost, iou);
    // K4+K5 fused: one block per (b,g)
    k_assign<<<dim3(BB * GG), blk, 0, stream>>>(cost, iou, lab, mmask);
    // K6
    k_loss<<<dim3((BB * AA + 255) / 256), blk, 0, stream>>>(pred, obj, cls, lab, cost, iou,
                                                            mmask, sps, accum);
    // K7
    k_final<<<1, 1, 0, stream>>>(accum, out);
}

// Round 3
// 472.196 us; speedup vs baseline: 2.7995x; 1.4321x over previous
//
#include <hip/hip_runtime.h>
#include <cstdint>
#include <cstddef>

#define BB 32
#define GG 50
#define CC 80
#define AA 8400
#define PCH (5 + CC)   // pred_output channels = 85
#define LP 11          // LDS list stride (pad 10 -> 11: conflict-free)
#define NLB ((BB * AA + 255) / 256)   // k_loss blocks = 1050

__device__ __forceinline__ float logsigf(float x) {
    // log_sigmoid(x) = min(x,0) - log1p(exp(-|x|))
    return fminf(x, 0.f) - log1pf(expf(-fabsf(x)));
}
__device__ __forceinline__ float softplusf(float x) {
    return fmaxf(x, 0.f) + log1pf(expf(-fabsf(x)));
}

// ---------------- K1: per-anchor class-sum precompute ----------------
__global__ void k_precompute(const float* __restrict__ obj, const float* __restrict__ cls,
                             float* __restrict__ s_neg, float* __restrict__ sps) {
    int i = blockIdx.x * blockDim.x + threadIdx.x;  // b*AA + a
    if (i >= BB * AA) return;
    float o = obj[i];
    float lo = logsigf(o);
    const float4* c4 = (const float4*)(cls + (size_t)i * CC);
    float sn = 0.f, sp = 0.f;
#pragma unroll
    for (int j4 = 0; j4 < CC / 4; j4++) {
        float4 v = c4[j4];
        float xs[4] = {v.x, v.y, v.z, v.w};
#pragma unroll
        for (int t = 0; t < 4; t++) {
            float x = xs[t];
            sp += softplusf(x);
            float lq = 0.5f * (logsigf(x) + lo);
            float q = expf(lq);
            q = fminf(fmaxf(q, 1e-7f), 1.f - 1e-7f);
            sn += log1pf(-q);
        }
    }
    s_neg[i] = sn;
    sps[i] = sp;
}

// ---------------- K2: geometry (fg0 + and_ctr bitmask) ----------------
__global__ void k_geom(const float* __restrict__ labels, const float* __restrict__ xs,
                       const float* __restrict__ ys, const float* __restrict__ ss,
                       int* __restrict__ fg0, unsigned long long* __restrict__ amask) {
    int b = blockIdx.y;
    int a = blockIdx.x * blockDim.x + threadIdx.x;
    __shared__ float lab[GG * 5];
    __shared__ int lv[GG];
    for (int t = threadIdx.x; t < GG * 5; t += blockDim.x) lab[t] = labels[b * GG * 5 + t];
    __syncthreads();
    if (threadIdx.x < GG) {
        const float* r = lab + threadIdx.x * 5;
        lv[threadIdx.x] = ((r[0] + r[1] + r[2] + r[3] + r[4]) > 0.f) ? 1 : 0;
    }
    __syncthreads();
    if (a >= AA) return;
    float s = ss[a];
    float xc = (xs[a] + 0.5f) * s;
    float yc = (ys[a] + 0.5f) * s;
    unsigned long long m = 0;
    int any = 0;
    for (int g = 0; g < GG; g++) {
        if (!lv[g]) continue;
        const float* r = lab + g * 5;
        float gx = r[1], gy = r[2], gw = r[3], gh = r[4];
        float d1 = xc - (gx - gw * 0.5f);
        float d2 = (gx + gw * 0.5f) - xc;
        float d3 = yc - (gy - gh * 0.5f);
        float d4 = (gy + gh * 0.5f) - yc;
        bool ib = fminf(fminf(d1, d2), fminf(d3, d4)) > 0.f;
        float cr = 2.5f * s;
        float e1 = xc - (gx - cr);
        float e2 = (gx + cr) - xc;
        float e3 = yc - (gy - cr);
        float e4 = (gy + cr) - yc;
        bool ic = fminf(fminf(e1, e2), fminf(e3, e4)) > 0.f;
        if (ib || ic) any = 1;
        if (ib && ic) m |= 1ull << g;
    }
    fg0[b * AA + a] = any;
    amask[b * AA + a] = m;
}

// ---------------- K3: cost + masked iou matrices ----------------
__global__ void k_cost(const float* __restrict__ pred, const float* __restrict__ obj,
                       const float* __restrict__ cls, const float* __restrict__ labels,
                       const float* __restrict__ s_neg, const int* __restrict__ fg0,
                       const unsigned long long* __restrict__ amask,
                       float* __restrict__ cost, float* __restrict__ iou) {
    int b = blockIdx.z, g = blockIdx.y;
    int a = blockIdx.x * blockDim.x + threadIdx.x;
    if (a >= AA) return;
    const float* r = labels + (size_t)(b * GG + g) * 5;
    float gcls = r[0], gx = r[1], gy = r[2], gw = r[3], gh = r[4];
    bool valid = (gcls + gx + gy + gw + gh) > 0.f;
    int gtc = (int)gcls;
    int ia = b * AA + a;
    const float* p = pred + (size_t)ia * PCH;
    float px = p[0], py = p[1], pw = p[2], ph = p[3];
    // pairwise IoU (cxcywh)
    float tlx = fmaxf(gx - gw * 0.5f, px - pw * 0.5f);
    float tly = fmaxf(gy - gh * 0.5f, py - ph * 0.5f);
    float brx = fminf(gx + gw * 0.5f, px + pw * 0.5f);
    float bry = fminf(gy + gh * 0.5f, py + ph * 0.5f);
    float en = (tlx < brx && tly < bry) ? 1.f : 0.f;
    float ai = (brx - tlx) * (bry - tly) * en;
    float v = ai / (gw * gh + pw * ph - ai + 1e-16f);
    int f0 = fg0[ia];
    v = v * (f0 ? 1.f : 0.f) * (valid ? 1.f : 0.f);
    // cls cost
    float o = obj[ia];
    float x = cls[(size_t)ia * CC + gtc];
    float lq = 0.5f * (logsigf(x) + logsigf(o));
    float q = fminf(fmaxf(expf(lq), 1e-7f), 1.f - 1e-7f);
    float cc = -logf(q) + log1pf(-q) - s_neg[ia];
    bool ac = (amask[ia] >> g) & 1ull;
    float cst = cc - 3.0f * logf(v + 1e-8f);
    cst += 100000.0f * (ac ? 0.f : 1.f);
    cst += 1000000000.0f * ((!f0 || !valid) ? 1.f : 0.f);
    size_t idx = (size_t)(b * GG + g) * AA + a;
    cost[idx] = cst;
    iou[idx] = v;
}

// ---------------- K4+K5 fused: single-pass dyn_k + top-k selection per (b,g) ----
__global__ void k_assign(const float* __restrict__ cost, const float* __restrict__ iou,
                         const float* __restrict__ labels,
                         unsigned long long* __restrict__ mmask) {
    int w = blockIdx.x;          // b*GG + g
    int b = w / GG, g = w % GG;
    const float* r = labels + (size_t)w * 5;
    if (!((r[0] + r[1] + r[2] + r[3] + r[4]) > 0.f)) return;  // invalid gt (uniform)
    int tid = threadIdx.x;
    const float* crow = cost + (size_t)w * AA;
    const float* irow = iou + (size_t)w * AA;

    float iv[10];
    float cv[10];
    int ci[10];
#pragma unroll
    for (int t = 0; t < 10; t++) { iv[t] = 0.f; cv[t] = 3.4e38f; ci[t] = AA; }

    for (int a = tid; a < AA; a += 256) {
        float u = irow[a];
        if (u > iv[9]) {
#pragma unroll
            for (int t = 0; t < 10; t++)
                if (u > iv[t]) { float tmp = iv[t]; iv[t] = u; u = tmp; }
        }
        float v = crow[a];
        int idx = a;
        if (v < cv[9] || (v == cv[9] && idx < ci[9])) {
#pragma unroll
            for (int t = 0; t < 10; t++) {
                bool sw = (v < cv[t]) || (v == cv[t] && idx < ci[t]);
                if (sw) {
                    float tf = cv[t]; cv[t] = v; v = tf;
                    int ti = ci[t]; ci[t] = idx; idx = ti;
                }
            }
        }
    }

    __shared__ float Lv[256 * LP];
    __shared__ int Li[256 * LP];
    __shared__ int s_k;

    // ---- Phase A: merge iou lists (descending), compute dyn_k ----
#pragma unroll
    for (int t = 0; t < 10; t++) Lv[tid * LP + t] = iv[t];
    __syncthreads();
    for (int n = 256; n > 1; n >>= 1) {
        float out[10];
        int half = n >> 1;
        if (tid < half) {
            int ia = (2 * tid) * LP, ib = (2 * tid + 1) * LP;
#pragma unroll
            for (int j = 0; j < 10; j++) {
                float av = Lv[ia], bv = Lv[ib];
                if (av >= bv) { out[j] = av; ia++; }
                else          { out[j] = bv; ib++; }
            }
        }
        __syncthreads();
        if (tid < half) {
#pragma unroll
            for (int j = 0; j < 10; j++) Lv[tid * LP + j] = out[j];
        }
        __syncthreads();
    }
    if (tid == 0) {
        float s = 0.f;
#pragma unroll
        for (int j = 0; j < 10; j++) s += Lv[j];
        int k = (int)s;
        if (k < 1) k = 1;
        s_k = k;
    }
    __syncthreads();

    // ---- Phase B: merge (cost, idx) lists (ascending, tie by lower idx) ----
#pragma unroll
    for (int t = 0; t < 10; t++) { Lv[tid * LP + t] = cv[t]; Li[tid * LP + t] = ci[t]; }
    __syncthreads();
    for (int n = 256; n > 1; n >>= 1) {
        float ov[10];
        int oi[10];
        int half = n >> 1;
        if (tid < half) {
            int ia = (2 * tid) * LP, ib = (2 * tid + 1) * LP;
#pragma unroll
            for (int j = 0; j < 10; j++) {
                float av = Lv[ia], bv = Lv[ib];
                int ax = Li[ia], bx = Li[ib];
                bool ta = (av < bv) || (av == bv && ax < bx);
                if (ta) { ov[j] = av; oi[j] = ax; ia++; }
                else    { ov[j] = bv; oi[j] = bx; ib++; }
            }
        }
        __syncthreads();
        if (tid < half) {
#pragma unroll
            for (int j = 0; j < 10; j++) { Lv[tid * LP + j] = ov[j]; Li[tid * LP + j] = oi[j]; }
        }
        __syncthreads();
    }

    if (tid < s_k) {
        atomicOr(&mmask[(size_t)b * AA + Li[tid]], 1ull << g);
    }
}

// ---------------- K6: resolve multi-match + loss partials (per-block, no atomics) ----
__global__ void k_loss(const float* __restrict__ pred, const float* __restrict__ obj,
                       const float* __restrict__ cls, const float* __restrict__ labels,
                       const float* __restrict__ cost, const float* __restrict__ iou,
                       const unsigned long long* __restrict__ mmask,
                       const float* __restrict__ sps, float* __restrict__ partial) {
    int i = blockIdx.x * blockDim.x + threadIdx.x;
    float li = 0.f, lo = 0.f, lc = 0.f, nf = 0.f;
    if (i < BB * AA) {
        int b = i / AA, a = i % AA;
        unsigned long long m = mmask[i];
        int cnt = __popcll(m);
        bool fg = (m != 0);
        int mg = 0;
        if (cnt > 1) {
            float bv = 3.4e38f;
            for (int g = 0; g < GG; g++) {
                float v = cost[(size_t)(b * GG + g) * AA + a];
                if (v < bv) { bv = v; mg = g; }
            }
        } else if (cnt == 1) {
            mg = __ffsll((unsigned long long)m) - 1;
        }
        float o = obj[i];
        lo = softplusf(o) - (fg ? o : 0.f);
        if (fg) {
            float piou = iou[(size_t)(b * GG + mg) * AA + a];
            const float* r = labels + (size_t)(b * GG + mg) * 5;
            int gtc = (int)r[0];
            float gx = r[1], gy = r[2], gw = r[3], gh = r[4];
            const float* p = pred + (size_t)i * PCH;
            float px = p[0], py = p[1], pw = p[2], ph = p[3];
            float tlx = fmaxf(px - pw * 0.5f, gx - gw * 0.5f);
            float tly = fmaxf(py - ph * 0.5f, gy - gh * 0.5f);
            float brx = fminf(px + pw * 0.5f, gx + gw * 0.5f);
            float bry = fminf(py + ph * 0.5f, gy + gh * 0.5f);
            float en = (tlx < brx && tly < bry) ? 1.f : 0.f;
            float ai = (brx - tlx) * (bry - tly) * en;
            float u = pw * ph + gw * gh - ai;
            float v2 = ai / (u + 1e-16f);
            li = 1.f - v2 * v2;
            lc = sps[i] - cls[(size_t)i * CC + gtc] * piou;
            nf = 1.f;
        }
    }
    // wave reduction
    for (int off = 32; off; off >>= 1) {
        li += __shfl_down(li, off);
        lo += __shfl_down(lo, off);
        lc += __shfl_down(lc, off);
        nf += __shfl_down(nf, off);
    }
    __shared__ float red[4][4];
    int wid = threadIdx.x >> 6;
    if ((threadIdx.x & 63) == 0) {
        red[wid][0] = li; red[wid][1] = lo; red[wid][2] = lc; red[wid][3] = nf;
    }
    __syncthreads();
    if (threadIdx.x == 0) {
        float s0 = 0.f, s1 = 0.f, s2 = 0.f, s3 = 0.f;
#pragma unroll
        for (int t = 0; t < 4; t++) {
            s0 += red[t][0]; s1 += red[t][1]; s2 += red[t][2]; s3 += red[t][3];
        }
        float4* pb = (float4*)partial;
        pb[blockIdx.x] = make_float4(s0, s1, s2, s3);
    }
}

// ---------------- K7: reduce partials, finalize ----------------
__global__ void k_final(const float* __restrict__ partial, float* __restrict__ out) {
    int tid = threadIdx.x;
    float s0 = 0.f, s1 = 0.f, s2 = 0.f, s3 = 0.f;
    const float4* pb = (const float4*)partial;
    for (int i = tid; i < NLB; i += 256) {
        float4 v = pb[i];
        s0 += v.x; s1 += v.y; s2 += v.z; s3 += v.w;
    }
    for (int off = 32; off; off >>= 1) {
        s0 += __shfl_down(s0, off);
        s1 += __shfl_down(s1, off);
        s2 += __shfl_down(s2, off);
        s3 += __shfl_down(s3, off);
    }
    __shared__ float red[4][4];
    int wid = tid >> 6;
    if ((tid & 63) == 0) {
        red[wid][0] = s0; red[wid][1] = s1; red[wid][2] = s2; red[wid][3] = s3;
    }
    __syncthreads();
    if (tid == 0) {
        float li = 0.f, lo = 0.f, lc = 0.f, nf = 0.f;
#pragma unroll
        for (int t = 0; t < 4; t++) {
            li += red[t][0]; lo += red[t][1]; lc += red[t][2]; nf += red[t][3];
        }
        nf = fmaxf(nf, 1.f);
        out[0] = (5.f * li + lo + lc) / nf;
    }
}

extern "C" void kernel_launch(void* const* d_in, const int* in_sizes, int n_in,
                              void* d_out, int out_size, void* d_ws, size_t ws_size,
                              hipStream_t stream) {
    const float* pred = (const float*)d_in[0];   // (B,A,85)
    const float* obj  = (const float*)d_in[1];   // (B,A,1)
    const float* cls  = (const float*)d_in[2];   // (B,A,80)
    const float* lab  = (const float*)d_in[3];   // (B,G,5)
    const float* xs   = (const float*)d_in[4];   // (A,)
    const float* ys   = (const float*)d_in[5];   // (A,)
    const float* ss   = (const float*)d_in[6];   // (A,)
    float* out = (float*)d_out;

    const size_t BA = (size_t)BB * AA;
    const size_t BGA = (size_t)BB * GG * AA;

    float* cost = (float*)d_ws;                    // BGA f32
    float* iou  = cost + BGA;                      // BGA f32
    float* sneg = iou + BGA;                       // BA f32
    float* sps  = sneg + BA;                       // BA f32
    int*   fg0  = (int*)(sps + BA);                // BA i32
    unsigned long long* amask = (unsigned long long*)(fg0 + BA);  // BA u64
    unsigned long long* mmask = amask + BA;        // BA u64
    float* partial = (float*)(mmask + BA);         // NLB*4 f32

    // zero the atomicOr destination
    hipMemsetAsync(mmask, 0, BA * sizeof(unsigned long long), stream);

    dim3 blk(256);
    // K1
    k_precompute<<<dim3((BB * AA + 255) / 256), blk, 0, stream>>>(obj, cls, sneg, sps);
    // K2
    k_geom<<<dim3((AA + 255) / 256, BB), blk, 0, stream>>>(lab, xs, ys, ss, fg0, amask);
    // K3
    k_cost<<<dim3((AA + 255) / 256, GG, BB), blk, 0, stream>>>(pred, obj, cls, lab, sneg,
                                                               fg0, amask, cost, iou);
    // K4+K5 fused: one block per (b,g)
    k_assign<<<dim3(BB * GG), blk, 0, stream>>>(cost, iou, lab, mmask);
    // K6: per-block partial sums, no atomics
    k_loss<<<dim3(NLB), blk, 0, stream>>>(pred, obj, cls, lab, cost, iou, mmask, sps, partial);
    // K7
    k_final<<<1, blk, 0, stream>>>(partial, out);
}

// Round 4
// 328.761 us; speedup vs baseline: 4.0209x; 1.4363x over previous
//
#include <hip/hip_runtime.h>
#include <cstdint>
#include <cstddef>

#define BB 32
#define GG 50
#define CC 80
#define AA 8400
#define PCH (5 + CC)   // pred_output channels = 85
#define LP 11          // LDS list stride (pad 10 -> 11: conflict-free)
#define NLB ((BB * AA + 255) / 256)   // k_loss blocks = 1050

// fast log(1+exp(-|x|)) shared term; returns l, sets sp=softplus(x), ls=logsig(x)
__device__ __forceinline__ void sp_ls(float x, float& sp, float& ls) {
    float e = __expf(-fabsf(x));        // exp(-|x|) in (0,1]
    float l = __logf(1.f + e);          // log1p(exp(-|x|)), arg in (1,2]: no cancellation
    sp = fmaxf(x, 0.f) + l;
    ls = fminf(x, 0.f) - l;
}
__device__ __forceinline__ float logsig_fast(float x) {
    float e = __expf(-fabsf(x));
    return fminf(x, 0.f) - __logf(1.f + e);
}
__device__ __forceinline__ float softplusf(float x) {
    // keep libm-accuracy version for the final loss terms (cheap: used once/elem)
    return fmaxf(x, 0.f) + log1pf(expf(-fabsf(x)));
}

// ---------------- K1: per-anchor class-sum precompute ----------------
__global__ void k_precompute(const float* __restrict__ obj, const float* __restrict__ cls,
                             float* __restrict__ s_neg, float* __restrict__ sps,
                             float* __restrict__ lobj) {
    int i = blockIdx.x * blockDim.x + threadIdx.x;  // b*AA + a
    if (i >= BB * AA) return;
    float o = obj[i];
    float lo = logsig_fast(o);
    lobj[i] = lo;
    const float4* c4 = (const float4*)(cls + (size_t)i * CC);
    float sn = 0.f, sp = 0.f;
#pragma unroll
    for (int j4 = 0; j4 < CC / 4; j4++) {
        float4 v = c4[j4];
        float xs[4] = {v.x, v.y, v.z, v.w};
#pragma unroll
        for (int t = 0; t < 4; t++) {
            float x = xs[t];
            float spx, lsx;
            sp_ls(x, spx, lsx);
            sp += spx;
            float q = __expf(0.5f * (lsx + lo));
            q = fminf(fmaxf(q, 1e-7f), 1.f - 1e-7f);
            sn += __logf(1.f - q);      // == log1p(-q): 1-q exact for q>=0.5 (Sterbenz)
        }
    }
    s_neg[i] = sn;
    sps[i] = sp;
}

// ---------------- K2: geometry (fg0 + and_ctr bitmask) ----------------
__global__ void k_geom(const float* __restrict__ labels, const float* __restrict__ xs,
                       const float* __restrict__ ys, const float* __restrict__ ss,
                       int* __restrict__ fg0, unsigned long long* __restrict__ amask) {
    int b = blockIdx.y;
    int a = blockIdx.x * blockDim.x + threadIdx.x;
    __shared__ float lab[GG * 5];
    __shared__ int lv[GG];
    for (int t = threadIdx.x; t < GG * 5; t += blockDim.x) lab[t] = labels[b * GG * 5 + t];
    __syncthreads();
    if (threadIdx.x < GG) {
        const float* r = lab + threadIdx.x * 5;
        lv[threadIdx.x] = ((r[0] + r[1] + r[2] + r[3] + r[4]) > 0.f) ? 1 : 0;
    }
    __syncthreads();
    if (a >= AA) return;
    float s = ss[a];
    float xc = (xs[a] + 0.5f) * s;
    float yc = (ys[a] + 0.5f) * s;
    unsigned long long m = 0;
    int any = 0;
    for (int g = 0; g < GG; g++) {
        if (!lv[g]) continue;
        const float* r = lab + g * 5;
        float gx = r[1], gy = r[2], gw = r[3], gh = r[4];
        float d1 = xc - (gx - gw * 0.5f);
        float d2 = (gx + gw * 0.5f) - xc;
        float d3 = yc - (gy - gh * 0.5f);
        float d4 = (gy + gh * 0.5f) - yc;
        bool ib = fminf(fminf(d1, d2), fminf(d3, d4)) > 0.f;
        float cr = 2.5f * s;
        float e1 = xc - (gx - cr);
        float e2 = (gx + cr) - xc;
        float e3 = yc - (gy - cr);
        float e4 = (gy + cr) - yc;
        bool ic = fminf(fminf(e1, e2), fminf(e3, e4)) > 0.f;
        if (ib || ic) any = 1;
        if (ib && ic) m |= 1ull << g;
    }
    fg0[b * AA + a] = any;
    amask[b * AA + a] = m;
}

// ---------------- K3: cost + masked iou matrices ----------------
__global__ void k_cost(const float* __restrict__ pred, const float* __restrict__ lobj,
                       const float* __restrict__ cls, const float* __restrict__ labels,
                       const float* __restrict__ s_neg, const int* __restrict__ fg0,
                       const unsigned long long* __restrict__ amask,
                       float* __restrict__ cost, float* __restrict__ iou) {
    int b = blockIdx.z, g = blockIdx.y;
    int a = blockIdx.x * blockDim.x + threadIdx.x;
    if (a >= AA) return;
    const float* r = labels + (size_t)(b * GG + g) * 5;
    float gcls = r[0], gx = r[1], gy = r[2], gw = r[3], gh = r[4];
    bool valid = (gcls + gx + gy + gw + gh) > 0.f;
    int gtc = (int)gcls;
    int ia = b * AA + a;
    const float* p = pred + (size_t)ia * PCH;
    float px = p[0], py = p[1], pw = p[2], ph = p[3];
    // pairwise IoU (cxcywh)
    float tlx = fmaxf(gx - gw * 0.5f, px - pw * 0.5f);
    float tly = fmaxf(gy - gh * 0.5f, py - ph * 0.5f);
    float brx = fminf(gx + gw * 0.5f, px + pw * 0.5f);
    float bry = fminf(gy + gh * 0.5f, py + ph * 0.5f);
    float en = (tlx < brx && tly < bry) ? 1.f : 0.f;
    float ai = (brx - tlx) * (bry - tly) * en;
    float v = ai / (gw * gh + pw * ph - ai + 1e-16f);
    int f0 = fg0[ia];
    v = v * (f0 ? 1.f : 0.f) * (valid ? 1.f : 0.f);
    // cls cost
    float x = cls[(size_t)ia * CC + gtc];
    float lq = 0.5f * (logsig_fast(x) + lobj[ia]);
    float q = fminf(fmaxf(__expf(lq), 1e-7f), 1.f - 1e-7f);
    float cc = -__logf(q) + __logf(1.f - q) - s_neg[ia];
    bool ac = (amask[ia] >> g) & 1ull;
    float cst = cc - 3.0f * __logf(v + 1e-8f);
    cst += 100000.0f * (ac ? 0.f : 1.f);
    cst += 1000000000.0f * ((!f0 || !valid) ? 1.f : 0.f);
    size_t idx = (size_t)(b * GG + g) * AA + a;
    cost[idx] = cst;
    iou[idx] = v;
}

// ---------------- K4+K5 fused: single-pass dyn_k + top-k selection per (b,g) ----
__global__ void k_assign(const float* __restrict__ cost, const float* __restrict__ iou,
                         const float* __restrict__ labels,
                         unsigned long long* __restrict__ mmask) {
    int w = blockIdx.x;          // b*GG + g
    int b = w / GG, g = w % GG;
    const float* r = labels + (size_t)w * 5;
    if (!((r[0] + r[1] + r[2] + r[3] + r[4]) > 0.f)) return;  // invalid gt (uniform)
    int tid = threadIdx.x;
    const float* crow = cost + (size_t)w * AA;
    const float* irow = iou + (size_t)w * AA;

    float iv[10];
    float cv[10];
    int ci[10];
#pragma unroll
    for (int t = 0; t < 10; t++) { iv[t] = 0.f; cv[t] = 3.4e38f; ci[t] = AA; }

    for (int a = tid; a < AA; a += 256) {
        float u = irow[a];
        if (u > iv[9]) {
#pragma unroll
            for (int t = 0; t < 10; t++)
                if (u > iv[t]) { float tmp = iv[t]; iv[t] = u; u = tmp; }
        }
        float v = crow[a];
        int idx = a;
        if (v < cv[9] || (v == cv[9] && idx < ci[9])) {
#pragma unroll
            for (int t = 0; t < 10; t++) {
                bool sw = (v < cv[t]) || (v == cv[t] && idx < ci[t]);
                if (sw) {
                    float tf = cv[t]; cv[t] = v; v = tf;
                    int ti = ci[t]; ci[t] = idx; idx = ti;
                }
            }
        }
    }

    __shared__ float Lv[256 * LP];
    __shared__ int Li[256 * LP];
    __shared__ int s_k;

    // ---- Phase A: merge iou lists (descending), compute dyn_k ----
#pragma unroll
    for (int t = 0; t < 10; t++) Lv[tid * LP + t] = iv[t];
    __syncthreads();
    for (int n = 256; n > 1; n >>= 1) {
        float out[10];
        int half = n >> 1;
        if (tid < half) {
            int ia = (2 * tid) * LP, ib = (2 * tid + 1) * LP;
#pragma unroll
            for (int j = 0; j < 10; j++) {
                float av = Lv[ia], bv = Lv[ib];
                if (av >= bv) { out[j] = av; ia++; }
                else          { out[j] = bv; ib++; }
            }
        }
        __syncthreads();
        if (tid < half) {
#pragma unroll
            for (int j = 0; j < 10; j++) Lv[tid * LP + j] = out[j];
        }
        __syncthreads();
    }
    if (tid == 0) {
        float s = 0.f;
#pragma unroll
        for (int j = 0; j < 10; j++) s += Lv[j];
        int k = (int)s;
        if (k < 1) k = 1;
        s_k = k;
    }
    __syncthreads();

    // ---- Phase B: merge (cost, idx) lists (ascending, tie by lower idx) ----
#pragma unroll
    for (int t = 0; t < 10; t++) { Lv[tid * LP + t] = cv[t]; Li[tid * LP + t] = ci[t]; }
    __syncthreads();
    for (int n = 256; n > 1; n >>= 1) {
        float ov[10];
        int oi[10];
        int half = n >> 1;
        if (tid < half) {
            int ia = (2 * tid) * LP, ib = (2 * tid + 1) * LP;
#pragma unroll
            for (int j = 0; j < 10; j++) {
                float av = Lv[ia], bv = Lv[ib];
                int ax = Li[ia], bx = Li[ib];
                bool ta = (av < bv) || (av == bv && ax < bx);
                if (ta) { ov[j] = av; oi[j] = ax; ia++; }
                else    { ov[j] = bv; oi[j] = bx; ib++; }
            }
        }
        __syncthreads();
        if (tid < half) {
#pragma unroll
            for (int j = 0; j < 10; j++) { Lv[tid * LP + j] = ov[j]; Li[tid * LP + j] = oi[j]; }
        }
        __syncthreads();
    }

    if (tid < s_k) {
        atomicOr(&mmask[(size_t)b * AA + Li[tid]], 1ull << g);
    }
}

// ---------------- K6: resolve multi-match + loss partials (per-block, no atomics) ----
__global__ void k_loss(const float* __restrict__ pred, const float* __restrict__ obj,
                       const float* __restrict__ cls, const float* __restrict__ labels,
                       const float* __restrict__ cost, const float* __restrict__ iou,
                       const unsigned long long* __restrict__ mmask,
                       const float* __restrict__ sps, float* __restrict__ partial) {
    int i = blockIdx.x * blockDim.x + threadIdx.x;
    float li = 0.f, lo = 0.f, lc = 0.f, nf = 0.f;
    if (i < BB * AA) {
        int b = i / AA, a = i % AA;
        unsigned long long m = mmask[i];
        int cnt = __popcll(m);
        bool fg = (m != 0);
        int mg = 0;
        if (cnt > 1) {
            float bv = 3.4e38f;
            for (int g = 0; g < GG; g++) {
                float v = cost[(size_t)(b * GG + g) * AA + a];
                if (v < bv) { bv = v; mg = g; }
            }
        } else if (cnt == 1) {
            mg = __ffsll((unsigned long long)m) - 1;
        }
        float o = obj[i];
        lo = softplusf(o) - (fg ? o : 0.f);
        if (fg) {
            float piou = iou[(size_t)(b * GG + mg) * AA + a];
            const float* r = labels + (size_t)(b * GG + mg) * 5;
            int gtc = (int)r[0];
            float gx = r[1], gy = r[2], gw = r[3], gh = r[4];
            const float* p = pred + (size_t)i * PCH;
            float px = p[0], py = p[1], pw = p[2], ph = p[3];
            float tlx = fmaxf(px - pw * 0.5f, gx - gw * 0.5f);
            float tly = fmaxf(py - ph * 0.5f, gy - gh * 0.5f);
            float brx = fminf(px + pw * 0.5f, gx + gw * 0.5f);
            float bry = fminf(py + ph * 0.5f, gy + gh * 0.5f);
            float en = (tlx < brx && tly < bry) ? 1.f : 0.f;
            float ai = (brx - tlx) * (bry - tly) * en;
            float u = pw * ph + gw * gh - ai;
            float v2 = ai / (u + 1e-16f);
            li = 1.f - v2 * v2;
            lc = sps[i] - cls[(size_t)i * CC + gtc] * piou;
            nf = 1.f;
        }
    }
    // wave reduction
    for (int off = 32; off; off >>= 1) {
        li += __shfl_down(li, off);
        lo += __shfl_down(lo, off);
        lc += __shfl_down(lc, off);
        nf += __shfl_down(nf, off);
    }
    __shared__ float red[4][4];
    int wid = threadIdx.x >> 6;
    if ((threadIdx.x & 63) == 0) {
        red[wid][0] = li; red[wid][1] = lo; red[wid][2] = lc; red[wid][3] = nf;
    }
    __syncthreads();
    if (threadIdx.x == 0) {
        float s0 = 0.f, s1 = 0.f, s2 = 0.f, s3 = 0.f;
#pragma unroll
        for (int t = 0; t < 4; t++) {
            s0 += red[t][0]; s1 += red[t][1]; s2 += red[t][2]; s3 += red[t][3];
        }
        float4* pb = (float4*)partial;
        pb[blockIdx.x] = make_float4(s0, s1, s2, s3);
    }
}

// ---------------- K7: reduce partials, finalize ----------------
__global__ void k_final(const float* __restrict__ partial, float* __restrict__ out) {
    int tid = threadIdx.x;
    float s0 = 0.f, s1 = 0.f, s2 = 0.f, s3 = 0.f;
    const float4* pb = (const float4*)partial;
    for (int i = tid; i < NLB; i += 256) {
        float4 v = pb[i];
        s0 += v.x; s1 += v.y; s2 += v.z; s3 += v.w;
    }
    for (int off = 32; off; off >>= 1) {
        s0 += __shfl_down(s0, off);
        s1 += __shfl_down(s1, off);
        s2 += __shfl_down(s2, off);
        s3 += __shfl_down(s3, off);
    }
    __shared__ float red[4][4];
    int wid = tid >> 6;
    if ((tid & 63) == 0) {
        red[wid][0] = s0; red[wid][1] = s1; red[wid][2] = s2; red[wid][3] = s3;
    }
    __syncthreads();
    if (tid == 0) {
        float li = 0.f, lo = 0.f, lc = 0.f, nf = 0.f;
#pragma unroll
        for (int t = 0; t < 4; t++) {
            li += red[t][0]; lo += red[t][1]; lc += red[t][2]; nf += red[t][3];
        }
        nf = fmaxf(nf, 1.f);
        out[0] = (5.f * li + lo + lc) / nf;
    }
}

extern "C" void kernel_launch(void* const* d_in, const int* in_sizes, int n_in,
                              void* d_out, int out_size, void* d_ws, size_t ws_size,
                              hipStream_t stream) {
    const float* pred = (const float*)d_in[0];   // (B,A,85)
    const float* obj  = (const float*)d_in[1];   // (B,A,1)
    const float* cls  = (const float*)d_in[2];   // (B,A,80)
    const float* lab  = (const float*)d_in[3];   // (B,G,5)
    const float* xs   = (const float*)d_in[4];   // (A,)
    const float* ys   = (const float*)d_in[5];   // (A,)
    const float* ss   = (const float*)d_in[6];   // (A,)
    float* out = (float*)d_out;

    const size_t BA = (size_t)BB * AA;
    const size_t BGA = (size_t)BB * GG * AA;

    float* cost = (float*)d_ws;                    // BGA f32
    float* iou  = cost + BGA;                      // BGA f32
    float* sneg = iou + BGA;                       // BA f32
    float* sps  = sneg + BA;                       // BA f32
    float* lobj = sps + BA;                        // BA f32
    int*   fg0  = (int*)(lobj + BA);               // BA i32
    unsigned long long* amask = (unsigned long long*)(fg0 + BA);  // BA u64
    unsigned long long* mmask = amask + BA;        // BA u64
    float* partial = (float*)(mmask + BA);         // NLB*4 f32

    // zero the atomicOr destination
    hipMemsetAsync(mmask, 0, BA * sizeof(unsigned long long), stream);

    dim3 blk(256);
    // K1
    k_precompute<<<dim3((BB * AA + 255) / 256), blk, 0, stream>>>(obj, cls, sneg, sps, lobj);
    // K2
    k_geom<<<dim3((AA + 255) / 256, BB), blk, 0, stream>>>(lab, xs, ys, ss, fg0, amask);
    // K3
    k_cost<<<dim3((AA + 255) / 256, GG, BB), blk, 0, stream>>>(pred, lobj, cls, lab, sneg,
                                                               fg0, amask, cost, iou);
    // K4+K5 fused: one block per (b,g)
    k_assign<<<dim3(BB * GG), blk, 0, stream>>>(cost, iou, lab, mmask);
    // K6: per-block partial sums, no atomics
    k_loss<<<dim3(NLB), blk, 0, stream>>>(pred, obj, cls, lab, cost, iou, mmask, sps, partial);
    // K7
    k_final<<<1, blk, 0, stream>>>(partial, out);
}

// Round 5
// 255.423 us; speedup vs baseline: 5.1754x; 1.2871x over previous
//
#include <hip/hip_runtime.h>
#include <cstdint>
#include <cstddef>

#define BB 32
#define GG 50
#define CC 80
#define AA 8400
#define PCH (5 + CC)   // pred_output channels = 85
#define LP 11          // LDS list stride (pad 10 -> 11: conflict-free)
#define NLB ((BB * AA + 255) / 256)   // k_loss blocks = 1050

__device__ __forceinline__ float logsig_fast(float x) {
    float e = __expf(-fabsf(x));
    return fminf(x, 0.f) - __logf(1.f + e);
}
__device__ __forceinline__ void sp_ls(float x, float& sp, float& ls) {
    float e = __expf(-fabsf(x));        // exp(-|x|) in (0,1]
    float l = __logf(1.f + e);          // log1p(exp(-|x|)), arg in (1,2]
    sp = fmaxf(x, 0.f) + l;
    ls = fminf(x, 0.f) - l;
}
__device__ __forceinline__ float softplusf(float x) {
    return fmaxf(x, 0.f) + log1pf(expf(-fabsf(x)));
}

// ---- shared value functions (MUST be identical between k_assign and k_loss) ----
__device__ __forceinline__ float pair_iou(float px, float py, float pw, float ph,
                                          float gx, float gy, float gw, float gh) {
    float tlx = fmaxf(gx - gw * 0.5f, px - pw * 0.5f);
    float tly = fmaxf(gy - gh * 0.5f, py - ph * 0.5f);
    float brx = fminf(gx + gw * 0.5f, px + pw * 0.5f);
    float bry = fminf(gy + gh * 0.5f, py + ph * 0.5f);
    float en = (tlx < brx && tly < bry) ? 1.f : 0.f;
    float ai = (brx - tlx) * (bry - tly) * en;
    return ai / (gw * gh + pw * ph - ai + 1e-16f);
}
__device__ __forceinline__ float cost_val(float x /*cls logit*/, float lo /*logsig(obj)*/,
                                          float sn /*s_neg*/, float v /*masked iou*/,
                                          bool ac, bool f0, bool valid) {
    float lq = 0.5f * (logsig_fast(x) + lo);
    float q = fminf(fmaxf(__expf(lq), 1e-7f), 1.f - 1e-7f);
    float cst = -__logf(q) + __logf(1.f - q) - sn;
    cst -= 3.0f * __logf(v + 1e-8f);
    cst += 100000.0f * (ac ? 0.f : 1.f);
    cst += 1000000000.0f * ((!f0 || !valid) ? 1.f : 0.f);
    return cst;
}

// ---------------- K1: per-anchor precompute (s_neg, sum softplus, logsig(obj), pbox) ----
__global__ void k_precompute(const float* __restrict__ pred, const float* __restrict__ obj,
                             const float* __restrict__ cls,
                             float* __restrict__ s_neg, float* __restrict__ sps,
                             float* __restrict__ lobj, float4* __restrict__ pbox) {
    int i = blockIdx.x * blockDim.x + threadIdx.x;  // b*AA + a
    if (i >= BB * AA) return;
    float o = obj[i];
    float lo = logsig_fast(o);
    lobj[i] = lo;
    const float* p = pred + (size_t)i * PCH;
    pbox[i] = make_float4(p[0], p[1], p[2], p[3]);
    const float4* c4 = (const float4*)(cls + (size_t)i * CC);
    float sn = 0.f, sp = 0.f;
#pragma unroll
    for (int j4 = 0; j4 < CC / 4; j4++) {
        float4 v = c4[j4];
        float xs[4] = {v.x, v.y, v.z, v.w};
#pragma unroll
        for (int t = 0; t < 4; t++) {
            float x = xs[t];
            float spx, lsx;
            sp_ls(x, spx, lsx);
            sp += spx;
            float q = __expf(0.5f * (lsx + lo));
            q = fminf(fmaxf(q, 1e-7f), 1.f - 1e-7f);
            sn += __logf(1.f - q);
        }
    }
    s_neg[i] = sn;
    sps[i] = sp;
}

// ---------------- K2: geometry (fg0 + and_ctr bitmask) ----------------
__global__ void k_geom(const float* __restrict__ labels, const float* __restrict__ xs,
                       const float* __restrict__ ys, const float* __restrict__ ss,
                       int* __restrict__ fg0, unsigned long long* __restrict__ amask) {
    int b = blockIdx.y;
    int a = blockIdx.x * blockDim.x + threadIdx.x;
    __shared__ float lab[GG * 5];
    __shared__ int lv[GG];
    for (int t = threadIdx.x; t < GG * 5; t += blockDim.x) lab[t] = labels[b * GG * 5 + t];
    __syncthreads();
    if (threadIdx.x < GG) {
        const float* r = lab + threadIdx.x * 5;
        lv[threadIdx.x] = ((r[0] + r[1] + r[2] + r[3] + r[4]) > 0.f) ? 1 : 0;
    }
    __syncthreads();
    if (a >= AA) return;
    float s = ss[a];
    float xc = (xs[a] + 0.5f) * s;
    float yc = (ys[a] + 0.5f) * s;
    unsigned long long m = 0;
    int any = 0;
    for (int g = 0; g < GG; g++) {
        if (!lv[g]) continue;
        const float* r = lab + g * 5;
        float gx = r[1], gy = r[2], gw = r[3], gh = r[4];
        float d1 = xc - (gx - gw * 0.5f);
        float d2 = (gx + gw * 0.5f) - xc;
        float d3 = yc - (gy - gh * 0.5f);
        float d4 = (gy + gh * 0.5f) - yc;
        bool ib = fminf(fminf(d1, d2), fminf(d3, d4)) > 0.f;
        float cr = 2.5f * s;
        float e1 = xc - (gx - cr);
        float e2 = (gx + cr) - xc;
        float e3 = yc - (gy - cr);
        float e4 = (gy + cr) - yc;
        bool ic = fminf(fminf(e1, e2), fminf(e3, e4)) > 0.f;
        if (ib || ic) any = 1;
        if (ib && ic) m |= 1ull << g;
    }
    fg0[b * AA + a] = any;
    amask[b * AA + a] = m;
}

// ---------------- K3 (fused cost+assign): per (b,g) block, on-the-fly cost/iou ----
__global__ void k_assign(const float4* __restrict__ pbox, const float* __restrict__ lobj,
                         const float* __restrict__ s_neg, const float* __restrict__ cls,
                         const int* __restrict__ fg0,
                         const unsigned long long* __restrict__ amask,
                         const float* __restrict__ labels,
                         unsigned long long* __restrict__ mmask) {
    int w = blockIdx.x;          // b*GG + g
    int b = w / GG, g = w % GG;
    const float* r = labels + (size_t)w * 5;
    float gcls = r[0], gx = r[1], gy = r[2], gw = r[3], gh = r[4];
    if (!((gcls + gx + gy + gw + gh) > 0.f)) return;  // invalid gt (uniform exit)
    int gtc = (int)gcls;
    int tid = threadIdx.x;

    float iv[10];
    float cv[10];
    int ci[10];
#pragma unroll
    for (int t = 0; t < 10; t++) { iv[t] = 0.f; cv[t] = 3.4e38f; ci[t] = AA; }

    for (int a = tid; a < AA; a += 256) {
        int ia = b * AA + a;
        float4 pb = pbox[ia];
        int f0 = fg0[ia];
        float raw = pair_iou(pb.x, pb.y, pb.z, pb.w, gx, gy, gw, gh);
        float v = raw * (f0 ? 1.f : 0.f);   // valid==true here
        // iou top-10 (descending insert)
        float u = v;
        if (u > iv[9]) {
#pragma unroll
            for (int t = 0; t < 10; t++)
                if (u > iv[t]) { float tmp = iv[t]; iv[t] = u; u = tmp; }
        }
        // cost
        float x = cls[(size_t)ia * CC + gtc];
        bool ac = (amask[ia] >> g) & 1ull;
        float cst = cost_val(x, lobj[ia], s_neg[ia], v, ac, f0 != 0, true);
        int idx = a;
        if (cst < cv[9] || (cst == cv[9] && idx < ci[9])) {
#pragma unroll
            for (int t = 0; t < 10; t++) {
                bool sw = (cst < cv[t]) || (cst == cv[t] && idx < ci[t]);
                if (sw) {
                    float tf = cv[t]; cv[t] = cst; cst = tf;
                    int ti = ci[t]; ci[t] = idx; idx = ti;
                }
            }
        }
    }

    __shared__ float Lv[256 * LP];
    __shared__ int Li[256 * LP];
    __shared__ int s_k;

    // ---- Phase A: merge iou lists (descending), compute dyn_k ----
#pragma unroll
    for (int t = 0; t < 10; t++) Lv[tid * LP + t] = iv[t];
    __syncthreads();
    for (int n = 256; n > 1; n >>= 1) {
        float out[10];
        int half = n >> 1;
        if (tid < half) {
            int ia = (2 * tid) * LP, ib = (2 * tid + 1) * LP;
#pragma unroll
            for (int j = 0; j < 10; j++) {
                float av = Lv[ia], bv = Lv[ib];
                if (av >= bv) { out[j] = av; ia++; }
                else          { out[j] = bv; ib++; }
            }
        }
        __syncthreads();
        if (tid < half) {
#pragma unroll
            for (int j = 0; j < 10; j++) Lv[tid * LP + j] = out[j];
        }
        __syncthreads();
    }
    if (tid == 0) {
        float s = 0.f;
#pragma unroll
        for (int j = 0; j < 10; j++) s += Lv[j];
        int k = (int)s;
        if (k < 1) k = 1;
        s_k = k;
    }
    __syncthreads();

    // ---- Phase B: merge (cost, idx) lists (ascending, tie by lower idx) ----
#pragma unroll
    for (int t = 0; t < 10; t++) { Lv[tid * LP + t] = cv[t]; Li[tid * LP + t] = ci[t]; }
    __syncthreads();
    for (int n = 256; n > 1; n >>= 1) {
        float ov[10];
        int oi[10];
        int half = n >> 1;
        if (tid < half) {
            int ia = (2 * tid) * LP, ib = (2 * tid + 1) * LP;
#pragma unroll
            for (int j = 0; j < 10; j++) {
                float av = Lv[ia], bv = Lv[ib];
                int ax = Li[ia], bx = Li[ib];
                bool ta = (av < bv) || (av == bv && ax < bx);
                if (ta) { ov[j] = av; oi[j] = ax; ia++; }
                else    { ov[j] = bv; oi[j] = bx; ib++; }
            }
        }
        __syncthreads();
        if (tid < half) {
#pragma unroll
            for (int j = 0; j < 10; j++) { Lv[tid * LP + j] = ov[j]; Li[tid * LP + j] = oi[j]; }
        }
        __syncthreads();
    }

    if (tid < s_k) {
        atomicOr(&mmask[(size_t)b * AA + Li[tid]], 1ull << g);
    }
}

// ---------------- K6: resolve multi-match + loss partials (recomputes, no matrices) ----
__global__ void k_loss(const float4* __restrict__ pbox, const float* __restrict__ obj,
                       const float* __restrict__ cls, const float* __restrict__ labels,
                       const float* __restrict__ lobj, const float* __restrict__ s_neg,
                       const int* __restrict__ fg0,
                       const unsigned long long* __restrict__ amask,
                       const unsigned long long* __restrict__ mmask,
                       const float* __restrict__ sps, float* __restrict__ partial) {
    int i = blockIdx.x * blockDim.x + threadIdx.x;
    float li = 0.f, lo = 0.f, lc = 0.f, nf = 0.f;
    if (i < BB * AA) {
        int b = i / AA, a = i % AA;
        unsigned long long m = mmask[i];
        int cnt = __popcll(m);
        bool fg = (m != 0);
        int mg = 0;
        float4 pb = pbox[i];
        if (cnt > 1) {
            // argmin over ALL g of the cost column (reference semantics)
            int f0 = fg0[i];
            float lor = lobj[i], snr = s_neg[i];
            unsigned long long am = amask[i];
            float bv = 3.4e38f;
            for (int g = 0; g < GG; g++) {
                const float* r = labels + (size_t)(b * GG + g) * 5;
                float gcls = r[0], gx = r[1], gy = r[2], gw = r[3], gh = r[4];
                bool valid = (gcls + gx + gy + gw + gh) > 0.f;
                int gtc = (int)gcls;
                float raw = pair_iou(pb.x, pb.y, pb.z, pb.w, gx, gy, gw, gh);
                float v = raw * (f0 ? 1.f : 0.f) * (valid ? 1.f : 0.f);
                float x = cls[(size_t)i * CC + gtc];
                bool ac = (am >> g) & 1ull;
                float cst = cost_val(x, lor, snr, v, ac, f0 != 0, valid);
                if (cst < bv) { bv = cst; mg = g; }
            }
        } else if (cnt == 1) {
            mg = __ffsll((unsigned long long)m) - 1;
        }
        float o = obj[i];
        lo = softplusf(o) - (fg ? o : 0.f);
        if (fg) {
            const float* r = labels + (size_t)(b * GG + mg) * 5;
            float gcls = r[0], gx = r[1], gy = r[2], gw = r[3], gh = r[4];
            bool valid = (gcls + gx + gy + gw + gh) > 0.f;
            int gtc = (int)gcls;
            // pred_iou (masked, same as assignment pass)
            float piou = pair_iou(pb.x, pb.y, pb.z, pb.w, gx, gy, gw, gh)
                         * ((fg0[i] != 0) ? 1.f : 0.f) * (valid ? 1.f : 0.f);
            // giou-style loss recompute (reference epilogue arithmetic)
            float tlx = fmaxf(pb.x - pb.z * 0.5f, gx - gw * 0.5f);
            float tly = fmaxf(pb.y - pb.w * 0.5f, gy - gh * 0.5f);
            float brx = fminf(pb.x + pb.z * 0.5f, gx + gw * 0.5f);
            float bry = fminf(pb.y + pb.w * 0.5f, gy + gh * 0.5f);
            float en = (tlx < brx && tly < bry) ? 1.f : 0.f;
            float ai = (brx - tlx) * (bry - tly) * en;
            float u = pb.z * pb.w + gw * gh - ai;
            float v2 = ai / (u + 1e-16f);
            li = 1.f - v2 * v2;
            lc = sps[i] - cls[(size_t)i * CC + gtc] * piou;
            nf = 1.f;
        }
    }
    // wave reduction
    for (int off = 32; off; off >>= 1) {
        li += __shfl_down(li, off);
        lo += __shfl_down(lo, off);
        lc += __shfl_down(lc, off);
        nf += __shfl_down(nf, off);
    }
    __shared__ float red[4][4];
    int wid = threadIdx.x >> 6;
    if ((threadIdx.x & 63) == 0) {
        red[wid][0] = li; red[wid][1] = lo; red[wid][2] = lc; red[wid][3] = nf;
    }
    __syncthreads();
    if (threadIdx.x == 0) {
        float s0 = 0.f, s1 = 0.f, s2 = 0.f, s3 = 0.f;
#pragma unroll
        for (int t = 0; t < 4; t++) {
            s0 += red[t][0]; s1 += red[t][1]; s2 += red[t][2]; s3 += red[t][3];
        }
        float4* pb = (float4*)partial;
        pb[blockIdx.x] = make_float4(s0, s1, s2, s3);
    }
}

// ---------------- K7: reduce partials, finalize ----------------
__global__ void k_final(const float* __restrict__ partial, float* __restrict__ out) {
    int tid = threadIdx.x;
    float s0 = 0.f, s1 = 0.f, s2 = 0.f, s3 = 0.f;
    const float4* pb = (const float4*)partial;
    for (int i = tid; i < NLB; i += 256) {
        float4 v = pb[i];
        s0 += v.x; s1 += v.y; s2 += v.z; s3 += v.w;
    }
    for (int off = 32; off; off >>= 1) {
        s0 += __shfl_down(s0, off);
        s1 += __shfl_down(s1, off);
        s2 += __shfl_down(s2, off);
        s3 += __shfl_down(s3, off);
    }
    __shared__ float red[4][4];
    int wid = tid >> 6;
    if ((tid & 63) == 0) {
        red[wid][0] = s0; red[wid][1] = s1; red[wid][2] = s2; red[wid][3] = s3;
    }
    __syncthreads();
    if (tid == 0) {
        float li = 0.f, lo = 0.f, lc = 0.f, nf = 0.f;
#pragma unroll
        for (int t = 0; t < 4; t++) {
            li += red[t][0]; lo += red[t][1]; lc += red[t][2]; nf += red[t][3];
        }
        nf = fmaxf(nf, 1.f);
        out[0] = (5.f * li + lo + lc) / nf;
    }
}

extern "C" void kernel_launch(void* const* d_in, const int* in_sizes, int n_in,
                              void* d_out, int out_size, void* d_ws, size_t ws_size,
                              hipStream_t stream) {
    const float* pred = (const float*)d_in[0];   // (B,A,85)
    const float* obj  = (const float*)d_in[1];   // (B,A,1)
    const float* cls  = (const float*)d_in[2];   // (B,A,80)
    const float* lab  = (const float*)d_in[3];   // (B,G,5)
    const float* xs   = (const float*)d_in[4];   // (A,)
    const float* ys   = (const float*)d_in[5];   // (A,)
    const float* ss   = (const float*)d_in[6];   // (A,)
    float* out = (float*)d_out;

    const size_t BA = (size_t)BB * AA;

    float*  sneg = (float*)d_ws;                   // BA f32
    float*  sps  = sneg + BA;                      // BA f32
    float*  lobj = sps + BA;                       // BA f32
    float4* pbox = (float4*)(lobj + BA);           // BA f32x4
    int*    fg0  = (int*)(pbox + BA);              // BA i32
    unsigned long long* amask = (unsigned long long*)(fg0 + BA);  // BA u64
    unsigned long long* mmask = amask + BA;        // BA u64
    float* partial = (float*)(mmask + BA);         // NLB*4 f32

    // zero the atomicOr destination
    hipMemsetAsync(mmask, 0, BA * sizeof(unsigned long long), stream);

    dim3 blk(256);
    // K1
    k_precompute<<<dim3((BB * AA + 255) / 256), blk, 0, stream>>>(pred, obj, cls,
                                                                  sneg, sps, lobj, pbox);
    // K2
    k_geom<<<dim3((AA + 255) / 256, BB), blk, 0, stream>>>(lab, xs, ys, ss, fg0, amask);
    // K3 fused cost+assign: one block per (b,g)
    k_assign<<<dim3(BB * GG), blk, 0, stream>>>(pbox, lobj, sneg, cls, fg0, amask, lab, mmask);
    // K6: per-block partial sums, no atomics
    k_loss<<<dim3(NLB), blk, 0, stream>>>(pbox, obj, cls, lab, lobj, sneg, fg0, amask,
                                          mmask, sps, partial);
    // K7
    k_final<<<1, blk, 0, stream>>>(partial, out);
}

// Round 6
// 213.567 us; speedup vs baseline: 6.1897x; 1.1960x over previous
//
#include <hip/hip_runtime.h>
#include <cstdint>
#include <cstddef>

#define BB 32
#define GG 50
#define CC 80
#define AA 8400
#define PCH (5 + CC)   // pred_output channels = 85
#define LP 11          // LDS list stride (pad 10 -> 11: conflict-free)
#define NLB ((BB * AA + 255) / 256)   // k_loss blocks = 1050
#define NXCD 8
#define FGBIT 63       // fg0 folded into amask bit 63 (g uses bits 0..49)

__device__ __forceinline__ float logsig_fast(float x) {
    float e = __expf(-fabsf(x));
    return fminf(x, 0.f) - __logf(1.f + e);
}
__device__ __forceinline__ void sp_ls(float x, float& sp, float& ls) {
    float e = __expf(-fabsf(x));        // exp(-|x|) in (0,1]
    float l = __logf(1.f + e);          // log1p(exp(-|x|)), arg in (1,2]
    sp = fmaxf(x, 0.f) + l;
    ls = fminf(x, 0.f) - l;
}
__device__ __forceinline__ float softplusf(float x) {
    return fmaxf(x, 0.f) + log1pf(expf(-fabsf(x)));
}

// ---- shared value functions (MUST be identical between k_assign and k_loss) ----
__device__ __forceinline__ float pair_iou(float px, float py, float pw, float ph,
                                          float gx, float gy, float gw, float gh) {
    float tlx = fmaxf(gx - gw * 0.5f, px - pw * 0.5f);
    float tly = fmaxf(gy - gh * 0.5f, py - ph * 0.5f);
    float brx = fminf(gx + gw * 0.5f, px + pw * 0.5f);
    float bry = fminf(gy + gh * 0.5f, py + ph * 0.5f);
    float en = (tlx < brx && tly < bry) ? 1.f : 0.f;
    float ai = (brx - tlx) * (bry - tly) * en;
    return ai / (gw * gh + pw * ph - ai + 1e-16f);
}
__device__ __forceinline__ float cost_val(float x /*cls logit*/, float lo /*logsig(obj)*/,
                                          float sn /*s_neg*/, float v /*masked iou*/,
                                          bool ac, bool f0, bool valid) {
    float lq = 0.5f * (logsig_fast(x) + lo);
    float q = fminf(fmaxf(__expf(lq), 1e-7f), 1.f - 1e-7f);
    float cst = -__logf(q) + __logf(1.f - q) - sn;
    cst -= 3.0f * __logf(v + 1e-8f);
    cst += 100000.0f * (ac ? 0.f : 1.f);
    cst += 1000000000.0f * ((!f0 || !valid) ? 1.f : 0.f);
    return cst;
}

// ---------------- K1: per-anchor precompute (lsn=(lobj,s_neg), sps, pbox) ----
__global__ void k_precompute(const float* __restrict__ pred, const float* __restrict__ obj,
                             const float* __restrict__ cls,
                             float2* __restrict__ lsn, float* __restrict__ sps,
                             float4* __restrict__ pbox) {
    int i = blockIdx.x * blockDim.x + threadIdx.x;  // b*AA + a
    if (i >= BB * AA) return;
    float o = obj[i];
    float lo = logsig_fast(o);
    const float* p = pred + (size_t)i * PCH;
    pbox[i] = make_float4(p[0], p[1], p[2], p[3]);
    const float4* c4 = (const float4*)(cls + (size_t)i * CC);
    float sn = 0.f, sp = 0.f;
#pragma unroll
    for (int j4 = 0; j4 < CC / 4; j4++) {
        float4 v = c4[j4];
        float xs[4] = {v.x, v.y, v.z, v.w};
#pragma unroll
        for (int t = 0; t < 4; t++) {
            float x = xs[t];
            float spx, lsx;
            sp_ls(x, spx, lsx);
            sp += spx;
            float q = __expf(0.5f * (lsx + lo));
            q = fminf(fmaxf(q, 1e-7f), 1.f - 1e-7f);
            sn += __logf(1.f - q);
        }
    }
    lsn[i] = make_float2(lo, sn);
    sps[i] = sp;
}

// ---------------- K2: geometry (amask bits 0..49 = and_ctr, bit 63 = fg0) ----
__global__ void k_geom(const float* __restrict__ labels, const float* __restrict__ xs,
                       const float* __restrict__ ys, const float* __restrict__ ss,
                       unsigned long long* __restrict__ amask) {
    int b = blockIdx.y;
    int a = blockIdx.x * blockDim.x + threadIdx.x;
    __shared__ float lab[GG * 5];
    __shared__ int lv[GG];
    for (int t = threadIdx.x; t < GG * 5; t += blockDim.x) lab[t] = labels[b * GG * 5 + t];
    __syncthreads();
    if (threadIdx.x < GG) {
        const float* r = lab + threadIdx.x * 5;
        lv[threadIdx.x] = ((r[0] + r[1] + r[2] + r[3] + r[4]) > 0.f) ? 1 : 0;
    }
    __syncthreads();
    if (a >= AA) return;
    float s = ss[a];
    float xc = (xs[a] + 0.5f) * s;
    float yc = (ys[a] + 0.5f) * s;
    unsigned long long m = 0;
    int any = 0;
    for (int g = 0; g < GG; g++) {
        if (!lv[g]) continue;
        const float* r = lab + g * 5;
        float gx = r[1], gy = r[2], gw = r[3], gh = r[4];
        float d1 = xc - (gx - gw * 0.5f);
        float d2 = (gx + gw * 0.5f) - xc;
        float d3 = yc - (gy - gh * 0.5f);
        float d4 = (gy + gh * 0.5f) - yc;
        bool ib = fminf(fminf(d1, d2), fminf(d3, d4)) > 0.f;
        float cr = 2.5f * s;
        float e1 = xc - (gx - cr);
        float e2 = (gx + cr) - xc;
        float e3 = yc - (gy - cr);
        float e4 = (gy + cr) - yc;
        bool ic = fminf(fminf(e1, e2), fminf(e3, e4)) > 0.f;
        if (ib || ic) any = 1;
        if (ib && ic) m |= 1ull << g;
    }
    if (any) m |= 1ull << FGBIT;
    amask[b * AA + a] = m;
}

// ---------------- K3 (fused cost+assign): per (b,g) block, on-the-fly cost/iou ----
// blockIdx swizzled so all 50 blocks of one b land on one XCD (L2 reuse of
// the shared per-b anchor arrays + cls lines).
__global__ void k_assign(const float4* __restrict__ pbox, const float2* __restrict__ lsn,
                         const float* __restrict__ cls,
                         const unsigned long long* __restrict__ amask,
                         const float* __restrict__ labels,
                         unsigned long long* __restrict__ mmask) {
    // XCD-aware swizzle: hw round-robin (bid % 8 -> XCD) => XCD x gets
    // logical w in [x*200, (x+1)*200) = b in [4x, 4x+4).  1600 % 8 == 0.
    int bid = blockIdx.x;
    int w = (bid % NXCD) * (BB * GG / NXCD) + bid / NXCD;
    int b = w / GG, g = w % GG;
    const float* r = labels + (size_t)w * 5;
    float gcls = r[0], gx = r[1], gy = r[2], gw = r[3], gh = r[4];
    if (!((gcls + gx + gy + gw + gh) > 0.f)) return;  // invalid gt (uniform exit)
    int gtc = (int)gcls;
    int tid = threadIdx.x;

    float iv[10];
    float cv[10];
    int ci[10];
#pragma unroll
    for (int t = 0; t < 10; t++) { iv[t] = 0.f; cv[t] = 3.4e38f; ci[t] = AA; }

    for (int a = tid; a < AA; a += 256) {
        int ia = b * AA + a;
        float4 pb = pbox[ia];
        unsigned long long am = amask[ia];
        bool f0 = (am >> FGBIT) & 1ull;
        float raw = pair_iou(pb.x, pb.y, pb.z, pb.w, gx, gy, gw, gh);
        float v = raw * (f0 ? 1.f : 0.f);   // valid==true here
        // iou top-10 (descending insert)
        float u = v;
        if (u > iv[9]) {
#pragma unroll
            for (int t = 0; t < 10; t++)
                if (u > iv[t]) { float tmp = iv[t]; iv[t] = u; u = tmp; }
        }
        // cost
        float x = cls[(size_t)ia * CC + gtc];
        float2 ls = lsn[ia];
        bool ac = (am >> g) & 1ull;
        float cst = cost_val(x, ls.x, ls.y, v, ac, f0, true);
        int idx = a;
        if (cst < cv[9] || (cst == cv[9] && idx < ci[9])) {
#pragma unroll
            for (int t = 0; t < 10; t++) {
                bool sw = (cst < cv[t]) || (cst == cv[t] && idx < ci[t]);
                if (sw) {
                    float tf = cv[t]; cv[t] = cst; cst = tf;
                    int ti = ci[t]; ci[t] = idx; idx = ti;
                }
            }
        }
    }

    __shared__ float Lv[256 * LP];
    __shared__ int Li[256 * LP];
    __shared__ int s_k;

    // ---- Phase A: merge iou lists (descending), compute dyn_k ----
#pragma unroll
    for (int t = 0; t < 10; t++) Lv[tid * LP + t] = iv[t];
    __syncthreads();
    for (int n = 256; n > 1; n >>= 1) {
        float out[10];
        int half = n >> 1;
        if (tid < half) {
            int ia = (2 * tid) * LP, ib = (2 * tid + 1) * LP;
#pragma unroll
            for (int j = 0; j < 10; j++) {
                float av = Lv[ia], bv = Lv[ib];
                if (av >= bv) { out[j] = av; ia++; }
                else          { out[j] = bv; ib++; }
            }
        }
        __syncthreads();
        if (tid < half) {
#pragma unroll
            for (int j = 0; j < 10; j++) Lv[tid * LP + j] = out[j];
        }
        __syncthreads();
    }
    if (tid == 0) {
        float s = 0.f;
#pragma unroll
        for (int j = 0; j < 10; j++) s += Lv[j];
        int k = (int)s;
        if (k < 1) k = 1;
        s_k = k;
    }
    __syncthreads();

    // ---- Phase B: merge (cost, idx) lists (ascending, tie by lower idx) ----
#pragma unroll
    for (int t = 0; t < 10; t++) { Lv[tid * LP + t] = cv[t]; Li[tid * LP + t] = ci[t]; }
    __syncthreads();
    for (int n = 256; n > 1; n >>= 1) {
        float ov[10];
        int oi[10];
        int half = n >> 1;
        if (tid < half) {
            int ia = (2 * tid) * LP, ib = (2 * tid + 1) * LP;
#pragma unroll
            for (int j = 0; j < 10; j++) {
                float av = Lv[ia], bv = Lv[ib];
                int ax = Li[ia], bx = Li[ib];
                bool ta = (av < bv) || (av == bv && ax < bx);
                if (ta) { ov[j] = av; oi[j] = ax; ia++; }
                else    { ov[j] = bv; oi[j] = bx; ib++; }
            }
        }
        __syncthreads();
        if (tid < half) {
#pragma unroll
            for (int j = 0; j < 10; j++) { Lv[tid * LP + j] = ov[j]; Li[tid * LP + j] = oi[j]; }
        }
        __syncthreads();
    }

    if (tid < s_k) {
        atomicOr(&mmask[(size_t)b * AA + Li[tid]], 1ull << g);
    }
}

// ---------------- K6: resolve multi-match + loss partials (recomputes, no matrices) ----
__global__ void k_loss(const float4* __restrict__ pbox, const float* __restrict__ obj,
                       const float* __restrict__ cls, const float* __restrict__ labels,
                       const float2* __restrict__ lsn,
                       const unsigned long long* __restrict__ amask,
                       const unsigned long long* __restrict__ mmask,
                       const float* __restrict__ sps, float* __restrict__ partial) {
    int i = blockIdx.x * blockDim.x + threadIdx.x;
    float li = 0.f, lo = 0.f, lc = 0.f, nf = 0.f;
    if (i < BB * AA) {
        int b = i / AA, a = i % AA;
        unsigned long long m = mmask[i];
        int cnt = __popcll(m);
        bool fg = (m != 0);
        int mg = 0;
        float4 pb = pbox[i];
        unsigned long long am = amask[i];
        bool f0 = (am >> FGBIT) & 1ull;
        if (cnt > 1) {
            // argmin over ALL g of the cost column (reference semantics)
            float2 ls = lsn[i];
            float bv = 3.4e38f;
            for (int g = 0; g < GG; g++) {
                const float* r = labels + (size_t)(b * GG + g) * 5;
                float gcls = r[0], gx = r[1], gy = r[2], gw = r[3], gh = r[4];
                bool valid = (gcls + gx + gy + gw + gh) > 0.f;
                int gtc = (int)gcls;
                float raw = pair_iou(pb.x, pb.y, pb.z, pb.w, gx, gy, gw, gh);
                float v = raw * (f0 ? 1.f : 0.f) * (valid ? 1.f : 0.f);
                float x = cls[(size_t)i * CC + gtc];
                bool ac = (am >> g) & 1ull;
                float cst = cost_val(x, ls.x, ls.y, v, ac, f0, valid);
                if (cst < bv) { bv = cst; mg = g; }
            }
        } else if (cnt == 1) {
            mg = __ffsll((unsigned long long)m) - 1;
        }
        float o = obj[i];
        lo = softplusf(o) - (fg ? o : 0.f);
        if (fg) {
            const float* r = labels + (size_t)(b * GG + mg) * 5;
            float gcls = r[0], gx = r[1], gy = r[2], gw = r[3], gh = r[4];
            bool valid = (gcls + gx + gy + gw + gh) > 0.f;
            int gtc = (int)gcls;
            // pred_iou (masked, same as assignment pass)
            float piou = pair_iou(pb.x, pb.y, pb.z, pb.w, gx, gy, gw, gh)
                         * (f0 ? 1.f : 0.f) * (valid ? 1.f : 0.f);
            // iou loss recompute (reference epilogue arithmetic)
            float tlx = fmaxf(pb.x - pb.z * 0.5f, gx - gw * 0.5f);
            float tly = fmaxf(pb.y - pb.w * 0.5f, gy - gh * 0.5f);
            float brx = fminf(pb.x + pb.z * 0.5f, gx + gw * 0.5f);
            float bry = fminf(pb.y + pb.w * 0.5f, gy + gh * 0.5f);
            float en = (tlx < brx && tly < bry) ? 1.f : 0.f;
            float ai = (brx - tlx) * (bry - tly) * en;
            float u = pb.z * pb.w + gw * gh - ai;
            float v2 = ai / (u + 1e-16f);
            li = 1.f - v2 * v2;
            lc = sps[i] - cls[(size_t)i * CC + gtc] * piou;
            nf = 1.f;
        }
    }
    // wave reduction
    for (int off = 32; off; off >>= 1) {
        li += __shfl_down(li, off);
        lo += __shfl_down(lo, off);
        lc += __shfl_down(lc, off);
        nf += __shfl_down(nf, off);
    }
    __shared__ float red[4][4];
    int wid = threadIdx.x >> 6;
    if ((threadIdx.x & 63) == 0) {
        red[wid][0] = li; red[wid][1] = lo; red[wid][2] = lc; red[wid][3] = nf;
    }
    __syncthreads();
    if (threadIdx.x == 0) {
        float s0 = 0.f, s1 = 0.f, s2 = 0.f, s3 = 0.f;
#pragma unroll
        for (int t = 0; t < 4; t++) {
            s0 += red[t][0]; s1 += red[t][1]; s2 += red[t][2]; s3 += red[t][3];
        }
        float4* pb = (float4*)partial;
        pb[blockIdx.x] = make_float4(s0, s1, s2, s3);
    }
}

// ---------------- K7: reduce partials, finalize ----------------
__global__ void k_final(const float* __restrict__ partial, float* __restrict__ out) {
    int tid = threadIdx.x;
    float s0 = 0.f, s1 = 0.f, s2 = 0.f, s3 = 0.f;
    const float4* pb = (const float4*)partial;
    for (int i = tid; i < NLB; i += 256) {
        float4 v = pb[i];
        s0 += v.x; s1 += v.y; s2 += v.z; s3 += v.w;
    }
    for (int off = 32; off; off >>= 1) {
        s0 += __shfl_down(s0, off);
        s1 += __shfl_down(s1, off);
        s2 += __shfl_down(s2, off);
        s3 += __shfl_down(s3, off);
    }
    __shared__ float red[4][4];
    int wid = tid >> 6;
    if ((tid & 63) == 0) {
        red[wid][0] = s0; red[wid][1] = s1; red[wid][2] = s2; red[wid][3] = s3;
    }
    __syncthreads();
    if (tid == 0) {
        float li = 0.f, lo = 0.f, lc = 0.f, nf = 0.f;
#pragma unroll
        for (int t = 0; t < 4; t++) {
            li += red[t][0]; lo += red[t][1]; lc += red[t][2]; nf += red[t][3];
        }
        nf = fmaxf(nf, 1.f);
        out[0] = (5.f * li + lo + lc) / nf;
    }
}

extern "C" void kernel_launch(void* const* d_in, const int* in_sizes, int n_in,
                              void* d_out, int out_size, void* d_ws, size_t ws_size,
                              hipStream_t stream) {
    const float* pred = (const float*)d_in[0];   // (B,A,85)
    const float* obj  = (const float*)d_in[1];   // (B,A,1)
    const float* cls  = (const float*)d_in[2];   // (B,A,80)
    const float* lab  = (const float*)d_in[3];   // (B,G,5)
    const float* xs   = (const float*)d_in[4];   // (A,)
    const float* ys   = (const float*)d_in[5];   // (A,)
    const float* ss   = (const float*)d_in[6];   // (A,)
    float* out = (float*)d_out;

    const size_t BA = (size_t)BB * AA;

    float2* lsn  = (float2*)d_ws;                  // BA f32x2 (lobj, s_neg)
    float*  sps  = (float*)(lsn + BA);             // BA f32
    float4* pbox = (float4*)(sps + BA);            // BA f32x4
    unsigned long long* amask = (unsigned long long*)(pbox + BA);  // BA u64
    unsigned long long* mmask = amask + BA;        // BA u64
    float* partial = (float*)(mmask + BA);         // NLB*4 f32

    // zero the atomicOr destination
    hipMemsetAsync(mmask, 0, BA * sizeof(unsigned long long), stream);

    dim3 blk(256);
    // K1
    k_precompute<<<dim3((BB * AA + 255) / 256), blk, 0, stream>>>(pred, obj, cls,
                                                                  lsn, sps, pbox);
    // K2
    k_geom<<<dim3((AA + 255) / 256, BB), blk, 0, stream>>>(lab, xs, ys, ss, amask);
    // K3 fused cost+assign: one block per (b,g), XCD-swizzled
    k_assign<<<dim3(BB * GG), blk, 0, stream>>>(pbox, lsn, cls, amask, lab, mmask);
    // K6: per-block partial sums, no atomics
    k_loss<<<dim3(NLB), blk, 0, stream>>>(pbox, obj, cls, lab, lsn, amask,
                                          mmask, sps, partial);
    // K7
    k_final<<<1, blk, 0, stream>>>(partial, out);
}

// Round 7
// 203.167 us; speedup vs baseline: 6.5065x; 1.0512x over previous
//
#include <hip/hip_runtime.h>
#include <cstdint>
#include <cstddef>

#define BB 32
#define GG 50
#define CC 80
#define AA 8400
#define PCH (5 + CC)   // pred_output channels = 85
#define LP 11          // LDS list stride (pad 10 -> 11: conflict-free)
#define NLB ((BB * AA + 255) / 256)   // k_loss blocks = 1050
#define NXCD 8
#define FGBIT 63       // fg0 folded into amask bit 63 (g uses bits 0..49)
#define CH 4           // anchor chunks per (b,g)
#define CHA (AA / CH)  // 2100 anchors per chunk
#define S1B 128        // stage-1 block size

__device__ __forceinline__ float logsig_fast(float x) {
    float e = __expf(-fabsf(x));
    return fminf(x, 0.f) - __logf(1.f + e);
}
__device__ __forceinline__ void sp_ls(float x, float& sp, float& ls) {
    float e = __expf(-fabsf(x));        // exp(-|x|) in (0,1]
    float l = __logf(1.f + e);          // log1p(exp(-|x|)), arg in (1,2]
    sp = fmaxf(x, 0.f) + l;
    ls = fminf(x, 0.f) - l;
}
__device__ __forceinline__ float softplusf(float x) {
    return fmaxf(x, 0.f) + log1pf(expf(-fabsf(x)));
}

// ---- shared value functions (MUST be identical between k_assign1 and k_loss) ----
__device__ __forceinline__ float pair_iou(float px, float py, float pw, float ph,
                                          float gx, float gy, float gw, float gh) {
    float tlx = fmaxf(gx - gw * 0.5f, px - pw * 0.5f);
    float tly = fmaxf(gy - gh * 0.5f, py - ph * 0.5f);
    float brx = fminf(gx + gw * 0.5f, px + pw * 0.5f);
    float bry = fminf(gy + gh * 0.5f, py + ph * 0.5f);
    float en = (tlx < brx && tly < bry) ? 1.f : 0.f;
    float ai = (brx - tlx) * (bry - tly) * en;
    return ai / (gw * gh + pw * ph - ai + 1e-16f);
}
__device__ __forceinline__ float cost_val(float x /*cls logit*/, float lo /*logsig(obj)*/,
                                          float sn /*s_neg*/, float v /*masked iou*/,
                                          bool ac, bool f0, bool valid) {
    float lq = 0.5f * (logsig_fast(x) + lo);
    float q = fminf(fmaxf(__expf(lq), 1e-7f), 1.f - 1e-7f);
    float cst = -__logf(q) + __logf(1.f - q) - sn;
    cst -= 3.0f * __logf(v + 1e-8f);
    cst += 100000.0f * (ac ? 0.f : 1.f);
    cst += 1000000000.0f * ((!f0 || !valid) ? 1.f : 0.f);
    return cst;
}

// ---------------- K1: per-anchor precompute (lsn=(lobj,s_neg), sps, pbox) ----
__global__ void k_precompute(const float* __restrict__ pred, const float* __restrict__ obj,
                             const float* __restrict__ cls,
                             float2* __restrict__ lsn, float* __restrict__ sps,
                             float4* __restrict__ pbox) {
    int i = blockIdx.x * blockDim.x + threadIdx.x;  // b*AA + a
    if (i >= BB * AA) return;
    float o = obj[i];
    float lo = logsig_fast(o);
    const float* p = pred + (size_t)i * PCH;
    pbox[i] = make_float4(p[0], p[1], p[2], p[3]);
    const float4* c4 = (const float4*)(cls + (size_t)i * CC);
    float sn = 0.f, sp = 0.f;
#pragma unroll
    for (int j4 = 0; j4 < CC / 4; j4++) {
        float4 v = c4[j4];
        float xs[4] = {v.x, v.y, v.z, v.w};
#pragma unroll
        for (int t = 0; t < 4; t++) {
            float x = xs[t];
            float spx, lsx;
            sp_ls(x, spx, lsx);
            sp += spx;
            float q = __expf(0.5f * (lsx + lo));
            q = fminf(fmaxf(q, 1e-7f), 1.f - 1e-7f);
            sn += __logf(1.f - q);
        }
    }
    lsn[i] = make_float2(lo, sn);
    sps[i] = sp;
}

// ---------------- K2: geometry (amask bits 0..49 = and_ctr, bit 63 = fg0) ----
__global__ void k_geom(const float* __restrict__ labels, const float* __restrict__ xs,
                       const float* __restrict__ ys, const float* __restrict__ ss,
                       unsigned long long* __restrict__ amask) {
    int b = blockIdx.y;
    int a = blockIdx.x * blockDim.x + threadIdx.x;
    __shared__ float lab[GG * 5];
    __shared__ int lv[GG];
    for (int t = threadIdx.x; t < GG * 5; t += blockDim.x) lab[t] = labels[b * GG * 5 + t];
    __syncthreads();
    if (threadIdx.x < GG) {
        const float* r = lab + threadIdx.x * 5;
        lv[threadIdx.x] = ((r[0] + r[1] + r[2] + r[3] + r[4]) > 0.f) ? 1 : 0;
    }
    __syncthreads();
    if (a >= AA) return;
    float s = ss[a];
    float xc = (xs[a] + 0.5f) * s;
    float yc = (ys[a] + 0.5f) * s;
    unsigned long long m = 0;
    int any = 0;
    for (int g = 0; g < GG; g++) {
        if (!lv[g]) continue;
        const float* r = lab + g * 5;
        float gx = r[1], gy = r[2], gw = r[3], gh = r[4];
        float d1 = xc - (gx - gw * 0.5f);
        float d2 = (gx + gw * 0.5f) - xc;
        float d3 = yc - (gy - gh * 0.5f);
        float d4 = (gy + gh * 0.5f) - yc;
        bool ib = fminf(fminf(d1, d2), fminf(d3, d4)) > 0.f;
        float cr = 2.5f * s;
        float e1 = xc - (gx - cr);
        float e2 = (gx + cr) - xc;
        float e3 = yc - (gy - cr);
        float e4 = (gy + cr) - yc;
        bool ic = fminf(fminf(e1, e2), fminf(e3, e4)) > 0.f;
        if (ib || ic) any = 1;
        if (ib && ic) m |= 1ull << g;
    }
    if (any) m |= 1ull << FGBIT;
    amask[b * AA + a] = m;
}

// ---------------- K3 stage 1: per (b,g,chunk) partial top-10 lists ----------------
__global__ __launch_bounds__(S1B, 4)
void k_assign1(const float4* __restrict__ pbox, const float2* __restrict__ lsn,
               const float* __restrict__ cls,
               const unsigned long long* __restrict__ amask,
               const float* __restrict__ labels,
               float* __restrict__ pl) {
    // XCD swizzle: 6400 blocks, XCD x gets logical l in [800x, 800x+800)
    // => w in [200x, 200x+200) => b in [4x, 4x+4).
    int bid = blockIdx.x;
    int l = (bid % NXCD) * (BB * GG * CH / NXCD) + bid / NXCD;
    int w = l >> 2, c = l & 3;
    int b = w / GG, g = w % GG;
    const float* r = labels + (size_t)w * 5;
    float gcls = r[0], gx = r[1], gy = r[2], gw = r[3], gh = r[4];
    if (!((gcls + gx + gy + gw + gh) > 0.f)) return;  // invalid gt (uniform exit)
    int gtc = (int)gcls;
    int tid = threadIdx.x;

    float iv[10];
    float cv[10];
    int ci[10];
#pragma unroll
    for (int t = 0; t < 10; t++) { iv[t] = 0.f; cv[t] = 3.4e38f; ci[t] = AA; }

    int a0 = c * CHA, aend = a0 + CHA;
    for (int a = a0 + tid; a < aend; a += 2 * S1B) {
        int a2 = a + S1B;
        bool has2 = a2 < aend;
        int ia1 = b * AA + a;
        int ia2 = b * AA + (has2 ? a2 : a);
        // gather loads for both anchors up front (independent chains -> ILP)
        float4 p1 = pbox[ia1];
        float4 p2 = pbox[ia2];
        unsigned long long m1 = amask[ia1];
        unsigned long long m2 = amask[ia2];
        float2 s1 = lsn[ia1];
        float2 s2 = lsn[ia2];
        float x1 = cls[(size_t)ia1 * CC + gtc];
        float x2 = cls[(size_t)ia2 * CC + gtc];
        bool f01 = (m1 >> FGBIT) & 1ull;
        bool f02 = (m2 >> FGBIT) & 1ull;
        float v1 = pair_iou(p1.x, p1.y, p1.z, p1.w, gx, gy, gw, gh) * (f01 ? 1.f : 0.f);
        float v2 = pair_iou(p2.x, p2.y, p2.z, p2.w, gx, gy, gw, gh) * (f02 ? 1.f : 0.f);
        float c1 = cost_val(x1, s1.x, s1.y, v1, (m1 >> g) & 1ull, f01, true);
        float c2 = cost_val(x2, s2.x, s2.y, v2, (m2 >> g) & 1ull, f02, true);
        // insert anchor 1
        float u = v1;
        if (u > iv[9]) {
#pragma unroll
            for (int t = 0; t < 10; t++)
                if (u > iv[t]) { float tmp = iv[t]; iv[t] = u; u = tmp; }
        }
        int idx = a;
        if (c1 < cv[9] || (c1 == cv[9] && idx < ci[9])) {
#pragma unroll
            for (int t = 0; t < 10; t++) {
                bool sw = (c1 < cv[t]) || (c1 == cv[t] && idx < ci[t]);
                if (sw) {
                    float tf = cv[t]; cv[t] = c1; c1 = tf;
                    int ti = ci[t]; ci[t] = idx; idx = ti;
                }
            }
        }
        // insert anchor 2
        if (has2) {
            u = v2;
            if (u > iv[9]) {
#pragma unroll
                for (int t = 0; t < 10; t++)
                    if (u > iv[t]) { float tmp = iv[t]; iv[t] = u; u = tmp; }
            }
            idx = a2;
            if (c2 < cv[9] || (c2 == cv[9] && idx < ci[9])) {
#pragma unroll
                for (int t = 0; t < 10; t++) {
                    bool sw = (c2 < cv[t]) || (c2 == cv[t] && idx < ci[t]);
                    if (sw) {
                        float tf = cv[t]; cv[t] = c2; c2 = tf;
                        int ti = ci[t]; ci[t] = idx; idx = ti;
                    }
                }
            }
        }
    }

    __shared__ float Lv[S1B * LP];
    __shared__ int Li[S1B * LP];

    // ---- Phase A: merge iou lists (descending) ----
#pragma unroll
    for (int t = 0; t < 10; t++) Lv[tid * LP + t] = iv[t];
    __syncthreads();
    for (int n = S1B; n > 1; n >>= 1) {
        float out[10];
        int half = n >> 1;
        if (tid < half) {
            int ia = (2 * tid) * LP, ib = (2 * tid + 1) * LP;
#pragma unroll
            for (int j = 0; j < 10; j++) {
                float av = Lv[ia], bv = Lv[ib];
                if (av >= bv) { out[j] = av; ia++; }
                else          { out[j] = bv; ib++; }
            }
        }
        __syncthreads();
        if (tid < half) {
#pragma unroll
            for (int j = 0; j < 10; j++) Lv[tid * LP + j] = out[j];
        }
        __syncthreads();
    }
    if (tid < 10) pl[(size_t)l * 32 + tid] = Lv[tid];
    __syncthreads();

    // ---- Phase B: merge (cost, idx) lists (ascending, tie by lower idx) ----
#pragma unroll
    for (int t = 0; t < 10; t++) { Lv[tid * LP + t] = cv[t]; Li[tid * LP + t] = ci[t]; }
    __syncthreads();
    for (int n = S1B; n > 1; n >>= 1) {
        float ov[10];
        int oi[10];
        int half = n >> 1;
        if (tid < half) {
            int ia = (2 * tid) * LP, ib = (2 * tid + 1) * LP;
#pragma unroll
            for (int j = 0; j < 10; j++) {
                float av = Lv[ia], bv = Lv[ib];
                int ax = Li[ia], bx = Li[ib];
                bool ta = (av < bv) || (av == bv && ax < bx);
                if (ta) { ov[j] = av; oi[j] = ax; ia++; }
                else    { ov[j] = bv; oi[j] = bx; ib++; }
            }
        }
        __syncthreads();
        if (tid < half) {
#pragma unroll
            for (int j = 0; j < 10; j++) { Lv[tid * LP + j] = ov[j]; Li[tid * LP + j] = oi[j]; }
        }
        __syncthreads();
    }
    if (tid < 10) {
        pl[(size_t)l * 32 + 10 + tid] = Lv[tid];
        pl[(size_t)l * 32 + 20 + tid] = __int_as_float(Li[tid]);
    }
}

// ---------------- K3 stage 2: merge CH chunk lists per (b,g), dyn_k + atomicOr ----
__global__ void k_assign2(const float* __restrict__ labels, const float* __restrict__ pl,
                          unsigned long long* __restrict__ mmask) {
    int bid = blockIdx.x;
    int w = (bid % NXCD) * (BB * GG / NXCD) + bid / NXCD;
    int b = w / GG, g = w % GG;
    const float* r = labels + (size_t)w * 5;
    if (!((r[0] + r[1] + r[2] + r[3] + r[4]) > 0.f)) return;
    int tid = threadIdx.x;  // 64

    __shared__ float A[CH][10];
    __shared__ float Cv[CH][10];
    __shared__ int Ci[CH][10];
    __shared__ int s_k;
    __shared__ int sel[10];
    if (tid < CH * 10) {
        int c = tid / 10, j = tid % 10;
        const float* base = pl + ((size_t)w * CH + c) * 32;
        A[c][j] = base[j];
        Cv[c][j] = base[10 + j];
        Ci[c][j] = __float_as_int(base[20 + j]);
    }
    __syncthreads();
    if (tid == 0) {
        // 4-way merge (descending) for sum of global top-10 ious
        int h0 = 0, h1 = 0, h2 = 0, h3 = 0;
        float s = 0.f;
        for (int j = 0; j < 10; j++) {
            float a0 = (h0 < 10) ? A[0][h0] : -1.f;
            float a1 = (h1 < 10) ? A[1][h1] : -1.f;
            float a2 = (h2 < 10) ? A[2][h2] : -1.f;
            float a3 = (h3 < 10) ? A[3][h3] : -1.f;
            float bv = a0; int bc = 0;
            if (a1 > bv) { bv = a1; bc = 1; }
            if (a2 > bv) { bv = a2; bc = 2; }
            if (a3 > bv) { bv = a3; bc = 3; }
            s += bv;
            if (bc == 0) h0++; else if (bc == 1) h1++; else if (bc == 2) h2++; else h3++;
        }
        int k = (int)s;
        if (k < 1) k = 1;
        s_k = k;
        // 4-way merge (ascending lex) for global top-10 lowest costs
        h0 = h1 = h2 = h3 = 0;
        for (int j = 0; j < 10; j++) {
            float bv = 3.5e38f; int bix = 0x7fffffff; int bc = -1;
#pragma unroll
            for (int c = 0; c < CH; c++) {
                int h = (c == 0) ? h0 : (c == 1) ? h1 : (c == 2) ? h2 : h3;
                if (h < 10) {
                    float av = Cv[c][h];
                    int ax = Ci[c][h];
                    if (av < bv || (av == bv && ax < bix)) { bv = av; bix = ax; bc = c; }
                }
            }
            sel[j] = bix;
            if (bc == 0) h0++; else if (bc == 1) h1++; else if (bc == 2) h2++; else h3++;
        }
    }
    __syncthreads();
    if (tid < s_k) {
        atomicOr(&mmask[(size_t)b * AA + sel[tid]], 1ull << g);
    }
}

// ---------------- K6: resolve multi-match + loss partials (recomputes, no matrices) ----
__global__ void k_loss(const float4* __restrict__ pbox, const float* __restrict__ obj,
                       const float* __restrict__ cls, const float* __restrict__ labels,
                       const float2* __restrict__ lsn,
                       const unsigned long long* __restrict__ amask,
                       const unsigned long long* __restrict__ mmask,
                       const float* __restrict__ sps, float* __restrict__ partial) {
    int i = blockIdx.x * blockDim.x + threadIdx.x;
    float li = 0.f, lo = 0.f, lc = 0.f, nf = 0.f;
    if (i < BB * AA) {
        int b = i / AA, a = i % AA;
        unsigned long long m = mmask[i];
        int cnt = __popcll(m);
        bool fg = (m != 0);
        int mg = 0;
        float4 pb = pbox[i];
        unsigned long long am = amask[i];
        bool f0 = (am >> FGBIT) & 1ull;
        if (cnt > 1) {
            // argmin over ALL g of the cost column (reference semantics)
            float2 ls = lsn[i];
            float bv = 3.4e38f;
            for (int g = 0; g < GG; g++) {
                const float* r = labels + (size_t)(b * GG + g) * 5;
                float gcls = r[0], gx = r[1], gy = r[2], gw = r[3], gh = r[4];
                bool valid = (gcls + gx + gy + gw + gh) > 0.f;
                int gtc = (int)gcls;
                float raw = pair_iou(pb.x, pb.y, pb.z, pb.w, gx, gy, gw, gh);
                float v = raw * (f0 ? 1.f : 0.f) * (valid ? 1.f : 0.f);
                float x = cls[(size_t)i * CC + gtc];
                bool ac = (am >> g) & 1ull;
                float cst = cost_val(x, ls.x, ls.y, v, ac, f0, valid);
                if (cst < bv) { bv = cst; mg = g; }
            }
        } else if (cnt == 1) {
            mg = __ffsll((unsigned long long)m) - 1;
        }
        float o = obj[i];
        lo = softplusf(o) - (fg ? o : 0.f);
        if (fg) {
            const float* r = labels + (size_t)(b * GG + mg) * 5;
            float gcls = r[0], gx = r[1], gy = r[2], gw = r[3], gh = r[4];
            bool valid = (gcls + gx + gy + gw + gh) > 0.f;
            int gtc = (int)gcls;
            // pred_iou (masked, same as assignment pass)
            float piou = pair_iou(pb.x, pb.y, pb.z, pb.w, gx, gy, gw, gh)
                         * (f0 ? 1.f : 0.f) * (valid ? 1.f : 0.f);
            // iou loss recompute (reference epilogue arithmetic)
            float tlx = fmaxf(pb.x - pb.z * 0.5f, gx - gw * 0.5f);
            float tly = fmaxf(pb.y - pb.w * 0.5f, gy - gh * 0.5f);
            float brx = fminf(pb.x + pb.z * 0.5f, gx + gw * 0.5f);
            float bry = fminf(pb.y + pb.w * 0.5f, gy + gh * 0.5f);
            float en = (tlx < brx && tly < bry) ? 1.f : 0.f;
            float ai = (brx - tlx) * (bry - tly) * en;
            float u = pb.z * pb.w + gw * gh - ai;
            float v2 = ai / (u + 1e-16f);
            li = 1.f - v2 * v2;
            lc = sps[i] - cls[(size_t)i * CC + gtc] * piou;
            nf = 1.f;
        }
    }
    // wave reduction
    for (int off = 32; off; off >>= 1) {
        li += __shfl_down(li, off);
        lo += __shfl_down(lo, off);
        lc += __shfl_down(lc, off);
        nf += __shfl_down(nf, off);
    }
    __shared__ float red[4][4];
    int wid = threadIdx.x >> 6;
    if ((threadIdx.x & 63) == 0) {
        red[wid][0] = li; red[wid][1] = lo; red[wid][2] = lc; red[wid][3] = nf;
    }
    __syncthreads();
    if (threadIdx.x == 0) {
        float s0 = 0.f, s1 = 0.f, s2 = 0.f, s3 = 0.f;
#pragma unroll
        for (int t = 0; t < 4; t++) {
            s0 += red[t][0]; s1 += red[t][1]; s2 += red[t][2]; s3 += red[t][3];
        }
        float4* pb = (float4*)partial;
        pb[blockIdx.x] = make_float4(s0, s1, s2, s3);
    }
}

// ---------------- K7: reduce partials, finalize ----------------
__global__ void k_final(const float* __restrict__ partial, float* __restrict__ out) {
    int tid = threadIdx.x;
    float s0 = 0.f, s1 = 0.f, s2 = 0.f, s3 = 0.f;
    const float4* pb = (const float4*)partial;
    for (int i = tid; i < NLB; i += 256) {
        float4 v = pb[i];
        s0 += v.x; s1 += v.y; s2 += v.z; s3 += v.w;
    }
    for (int off = 32; off; off >>= 1) {
        s0 += __shfl_down(s0, off);
        s1 += __shfl_down(s1, off);
        s2 += __shfl_down(s2, off);
        s3 += __shfl_down(s3, off);
    }
    __shared__ float red[4][4];
    int wid = tid >> 6;
    if ((tid & 63) == 0) {
        red[wid][0] = s0; red[wid][1] = s1; red[wid][2] = s2; red[wid][3] = s3;
    }
    __syncthreads();
    if (tid == 0) {
        float li = 0.f, lo = 0.f, lc = 0.f, nf = 0.f;
#pragma unroll
        for (int t = 0; t < 4; t++) {
            li += red[t][0]; lo += red[t][1]; lc += red[t][2]; nf += red[t][3];
        }
        nf = fmaxf(nf, 1.f);
        out[0] = (5.f * li + lo + lc) / nf;
    }
}

extern "C" void kernel_launch(void* const* d_in, const int* in_sizes, int n_in,
                              void* d_out, int out_size, void* d_ws, size_t ws_size,
                              hipStream_t stream) {
    const float* pred = (const float*)d_in[0];   // (B,A,85)
    const float* obj  = (const float*)d_in[1];   // (B,A,1)
    const float* cls  = (const float*)d_in[2];   // (B,A,80)
    const float* lab  = (const float*)d_in[3];   // (B,G,5)
    const float* xs   = (const float*)d_in[4];   // (A,)
    const float* ys   = (const float*)d_in[5];   // (A,)
    const float* ss   = (const float*)d_in[6];   // (A,)
    float* out = (float*)d_out;

    const size_t BA = (size_t)BB * AA;

    float2* lsn  = (float2*)d_ws;                  // BA f32x2 (lobj, s_neg)
    float*  sps  = (float*)(lsn + BA);             // BA f32
    float4* pbox = (float4*)(sps + BA);            // BA f32x4
    unsigned long long* amask = (unsigned long long*)(pbox + BA);  // BA u64
    unsigned long long* mmask = amask + BA;        // BA u64
    float* partial = (float*)(mmask + BA);         // NLB*4 f32
    float* pl = partial + (size_t)NLB * 4;         // BB*GG*CH*32 f32 partial lists

    // zero the atomicOr destination
    hipMemsetAsync(mmask, 0, BA * sizeof(unsigned long long), stream);

    dim3 blk(256);
    // K1
    k_precompute<<<dim3((BB * AA + 255) / 256), blk, 0, stream>>>(pred, obj, cls,
                                                                  lsn, sps, pbox);
    // K2
    k_geom<<<dim3((AA + 255) / 256, BB), blk, 0, stream>>>(lab, xs, ys, ss, amask);
    // K3 stage 1: per (b,g,chunk) partial top-10, XCD-swizzled
    k_assign1<<<dim3(BB * GG * CH), dim3(S1B), 0, stream>>>(pbox, lsn, cls, amask, lab, pl);
    // K3 stage 2: merge chunk lists, dyn_k, select
    k_assign2<<<dim3(BB * GG), dim3(64), 0, stream>>>(lab, pl, mmask);
    // K6: per-block partial sums, no atomics
    k_loss<<<dim3(NLB), blk, 0, stream>>>(pbox, obj, cls, lab, lsn, amask,
                                          mmask, sps, partial);
    // K7
    k_final<<<1, blk, 0, stream>>>(partial, out);
}